// Round 5
// baseline (5420.421 us; speedup 1.0000x reference)
//
#include <hip/hip_runtime.h>
#include <stdint.h>

#define BB 64
#define TT 256
#define VV 32000
#define DD 512
#define HH 1024
#define FH 4096

// Padded U row stride: 2048 data bytes + 16 pad = 2064 (4-bank shift per row)
#define UROW 2064
#define UBLK (64 * UROW)   // 132096 bytes per WG

typedef float f32x4 __attribute__((ext_vector_type(4)));
typedef __bf16 bf16x8 __attribute__((ext_vector_type(8)));

typedef __attribute__((address_space(1))) void void_g;
typedef __attribute__((address_space(3))) void void_l;

static __device__ __forceinline__ void gload_lds16(const void* g, void* l) {
  __builtin_amdgcn_global_load_lds((const void_g*)g, (void_l*)l, 16, 0, 0);
}

static __device__ __forceinline__ unsigned short f2bf(float f) {
  union { float f; unsigned u; } x; x.f = f;
  unsigned r = x.u + 0x7FFFu + ((x.u >> 16) & 1u);
  return (unsigned short)(r >> 16);
}
static __device__ __forceinline__ float bf2f(unsigned short s) {
  union { unsigned u; float f; } x; x.u = ((unsigned)s) << 16;
  return x.f;
}
static __device__ __forceinline__ bf16x8 mk8(unsigned long long lo, unsigned long long hi) {
  union { unsigned long long q[2]; bf16x8 v; } x; x.q[0] = lo; x.q[1] = hi; return x.v;
}
static __device__ __forceinline__ float sigm(float x) {
  return 1.f / (1.f + __expf(-x));
}
static __device__ __forceinline__ float tanh_f(float x) {
  x = fminf(15.f, fmaxf(-15.f, x));
  float e = __expf(2.f * x);
  return (e - 1.f) / (e + 1.f);
}
static __device__ __forceinline__ float get_bf_u2(uint2 v, int u) {
  unsigned r = (u < 2) ? v.x : v.y;
  return bf2f((unsigned short)((u & 1) ? (r >> 16) : (r & 0xFFFFu)));
}

// ---------------- prep kernels ----------------

__global__ void k_cast_emb(const float* __restrict__ src, unsigned short* __restrict__ dst) {
  size_t i = ((size_t)blockIdx.x * 256 + threadIdx.x) * 8;
  float4 a = *(const float4*)(src + i);
  float4 b = *(const float4*)(src + i + 4);
  uint4 o;
  o.x = (unsigned)f2bf(a.x) | ((unsigned)f2bf(a.y) << 16);
  o.y = (unsigned)f2bf(a.z) | ((unsigned)f2bf(a.w) << 16);
  o.z = (unsigned)f2bf(b.x) | ((unsigned)f2bf(b.y) << 16);
  o.w = (unsigned)f2bf(b.z) | ((unsigned)f2bf(b.w) << 16);
  *(uint4*)(dst + i) = o;
}

// W_t[n'][k] bf16 (transposed, column-permuted), b_perm[n'] f32.
// n' = w*64 + g*16 + jj  <->  n = g*1024 + w*16 + jj
__global__ void k_prep_w(const float* __restrict__ Wsrc, const float* __restrict__ bsrc,
                         unsigned short* __restrict__ Wt, float* __restrict__ bperm) {
  int np = blockIdx.x;
  int w = np >> 6, r = np & 63, g = r >> 4, jj = r & 15;
  int n = g * 1024 + w * 16 + jj;
  int k0 = threadIdx.x * 4;
  unsigned short q0 = f2bf(Wsrc[(size_t)(k0 + 0) * FH + n]);
  unsigned short q1 = f2bf(Wsrc[(size_t)(k0 + 1) * FH + n]);
  unsigned short q2 = f2bf(Wsrc[(size_t)(k0 + 2) * FH + n]);
  unsigned short q3 = f2bf(Wsrc[(size_t)(k0 + 3) * FH + n]);
  uint2 o;
  o.x = (unsigned)q0 | ((unsigned)q1 << 16);
  o.y = (unsigned)q2 | ((unsigned)q3 << 16);
  *(uint2*)((char*)Wt + (size_t)np * 1024 + (size_t)k0 * 2) = o;
  if (threadIdx.x == 0) bperm[np] = bsrc[n];
}

// U_prep: per WG w, padded-linear LDS image: row j (64 rows) at j*UROW,
// 2048 bytes of bf16 U[n(j,w)][k] + 16 pad bytes (zeroed).
__global__ void k_prep_u(const float* __restrict__ Usrc, unsigned short* __restrict__ Uprep) {
  int bid = blockIdx.x;            // 0..4095 = w*64 + j
  int j = bid & 63;
  int w = bid >> 6;
  int g = j >> 4, jj = j & 15;
  int n = g * 1024 + w * 16 + jj;
  int k0 = threadIdx.x * 8;
  unsigned p[4];
  #pragma unroll
  for (int h = 0; h < 4; ++h) {
    unsigned short e0 = f2bf(Usrc[(size_t)(k0 + 2 * h) * FH + n]);
    unsigned short e1 = f2bf(Usrc[(size_t)(k0 + 2 * h + 1) * FH + n]);
    p[h] = (unsigned)e0 | ((unsigned)e1 << 16);
  }
  uint4 o; o.x = p[0]; o.y = p[1]; o.z = p[2]; o.w = p[3];
  char* dst = (char*)Uprep + (size_t)w * UBLK + (size_t)j * UROW;
  *(uint4*)(dst + threadIdx.x * 16) = o;
  if (threadIdx.x == 0) { uint4 z = {0, 0, 0, 0}; *(uint4*)(dst + 2048) = z; }
}

__global__ void k_mask(const int* __restrict__ tok, unsigned long long* __restrict__ mask64) {
  int t = threadIdx.x;
  unsigned long long m = 0;
  for (int b = 0; b < BB; ++b)
    m |= (unsigned long long)(tok[b * TT + t] != 0) << b;
  mask64[t] = m;
}

// ---------------- xW GEMM (gather fused) ----------------

__launch_bounds__(256)
__global__ void k_gemm_xw(const int* __restrict__ tok, const unsigned short* __restrict__ embb,
                          const unsigned short* __restrict__ Wt, const float* __restrict__ bperm,
                          unsigned short* __restrict__ xw) {
  __shared__ char As[16384];
  __shared__ char Bs[16384];
  __shared__ int toks[128];
  int tid = threadIdx.x, lane = tid & 63, wid = tid >> 6;
  int bm = blockIdx.x >> 5, bn = blockIdx.x & 31;
  if (tid < 128) toks[tid] = tok[bm * 128 + tid];
  int wm = wid >> 1, wn = wid & 1;
  f32x4 vz = {0.f, 0.f, 0.f, 0.f};
  f32x4 acc[4][4];
  #pragma unroll
  for (int i = 0; i < 4; ++i)
    #pragma unroll
    for (int j = 0; j < 4; ++j) acc[i][j] = vz;

  int kls = (lane >> 4) * 16;
  for (int ks = 0; ks < 8; ++ks) {
    __syncthreads();
    #pragma unroll
    for (int c = 0; c < 4; ++c) {
      int o = wid * 4096 + c * 1024 + lane * 16;
      int m = o >> 7, kl = o & 127;
      const char* ga = (const char*)embb + (size_t)toks[m] * 1024 + ks * 128 + (kl ^ ((m & 7) << 4));
      gload_lds16(ga, As + o);
      const char* gb = (const char*)Wt + (size_t)(bn * 128 + m) * 1024 + ks * 128 + (kl ^ ((m & 7) << 4));
      gload_lds16(gb, Bs + o);
    }
    asm volatile("s_waitcnt vmcnt(0)" ::: "memory");
    __syncthreads();
    #pragma unroll
    for (int tk = 0; tk < 2; ++tk) {
      bf16x8 af[4], bf[4];
      int kb = tk * 64 + kls;
      #pragma unroll
      for (int mt = 0; mt < 4; ++mt) {
        int m = wm * 64 + mt * 16 + (lane & 15);
        af[mt] = *(const bf16x8*)(As + m * 128 + (kb ^ ((m & 7) << 4)));
      }
      #pragma unroll
      for (int nt = 0; nt < 4; ++nt) {
        int n = wn * 64 + nt * 16 + (lane & 15);
        bf[nt] = *(const bf16x8*)(Bs + n * 128 + (kb ^ ((n & 7) << 4)));
      }
      #pragma unroll
      for (int mt = 0; mt < 4; ++mt)
        #pragma unroll
        for (int nt = 0; nt < 4; ++nt)
          acc[mt][nt] = __builtin_amdgcn_mfma_f32_16x16x32_bf16(af[mt], bf[nt], acc[mt][nt], 0, 0, 0);
    }
  }
  #pragma unroll
  for (int nt = 0; nt < 4; ++nt) {
    int col = bn * 128 + wn * 64 + nt * 16 + (lane & 15);
    float bias = bperm[col];
    #pragma unroll
    for (int mt = 0; mt < 4; ++mt) {
      #pragma unroll
      for (int r = 0; r < 4; ++r) {
        int row = bm * 128 + wm * 64 + mt * 16 + (lane >> 4) * 4 + r;
        xw[(size_t)row * FH + col] = f2bf(acc[mt][nt][r] + bias);
      }
    }
  }
}

// ---------------- persistent LSTM scan ----------------
// 64 WGs, WG w owns h cols [16w,16w+16). U resident in LDS (padded rows).
// h broadcast via per-step monotonic global buffers; consumers read them with
// compiler-tracked agent-coherent atomic loads -> NO acquire fence / buffer_inv.

#define LSTM_LDS (UBLK + 16640 + 4096 + 4096)

// One K-half: 64 coherent u64 loads (pipelined by issue order), then 16x4 MFMAs
#define HALF(TKB) do { \
  unsigned long long hb[64]; \
  _Pragma("unroll") \
  for (int tk = 0; tk < 16; ++tk) { \
    hb[tk * 2]      = __hip_atomic_load(h64 + b0i + ((TKB) + tk) * 8,     __ATOMIC_RELAXED, __HIP_MEMORY_SCOPE_AGENT); \
    hb[tk * 2 + 1]  = __hip_atomic_load(h64 + b0i + ((TKB) + tk) * 8 + 1, __ATOMIC_RELAXED, __HIP_MEMORY_SCOPE_AGENT); \
    hb[32 + tk * 2] = __hip_atomic_load(h64 + b1i + ((TKB) + tk) * 8,     __ATOMIC_RELAXED, __HIP_MEMORY_SCOPE_AGENT); \
    hb[33 + tk * 2] = __hip_atomic_load(h64 + b1i + ((TKB) + tk) * 8 + 1, __ATOMIC_RELAXED, __HIP_MEMORY_SCOPE_AGENT); \
  } \
  _Pragma("unroll") \
  for (int tk = 0; tk < 16; ++tk) { \
    bf16x8 b0_ = *(const bf16x8*)(Us + bo0 + ((TKB) + tk) * 64); \
    bf16x8 b1_ = *(const bf16x8*)(Us + bo1 + ((TKB) + tk) * 64); \
    bf16x8 a0_ = mk8(hb[tk * 2], hb[tk * 2 + 1]); \
    bf16x8 a1_ = mk8(hb[32 + tk * 2], hb[33 + tk * 2]); \
    a00 = __builtin_amdgcn_mfma_f32_16x16x32_bf16(a0_, b0_, a00, 0, 0, 0); \
    a01 = __builtin_amdgcn_mfma_f32_16x16x32_bf16(a0_, b1_, a01, 0, 0, 0); \
    a10 = __builtin_amdgcn_mfma_f32_16x16x32_bf16(a1_, b0_, a10, 0, 0, 0); \
    a11 = __builtin_amdgcn_mfma_f32_16x16x32_bf16(a1_, b1_, a11, 0, 0, 0); \
  } \
} while (0)

__launch_bounds__(256, 1)
__global__ void k_lstm(const unsigned short* __restrict__ Uprep, const unsigned short* __restrict__ xw,
                       const unsigned long long* __restrict__ mask64,
                       unsigned short* __restrict__ hseq, unsigned* __restrict__ flags,
                       float* __restrict__ hfin) {
  extern __shared__ char smem[];
  char* Us = smem;
  float* zl = (float*)(smem + UBLK);                 // [64][65] f32
  float* cb = (float*)(smem + UBLK + 16640);         // [64][16] f32
  float* ho = (float*)(smem + UBLK + 16640 + 4096);  // [64][16] f32
  int tid = threadIdx.x, lane = tid & 63, wid = tid >> 6;
  int w = blockIdx.x;

  {
    const char* src = (const char*)Uprep + (size_t)w * UBLK;
    #pragma unroll
    for (int c = 0; c < 32; ++c) {
      int o = c * 4096 + tid * 16;
      gload_lds16(src + o, Us + o);
    }
    if (wid == 0) {  // tail: 1024 bytes
      int o = 131072 + lane * 16;
      gload_lds16(src + o, Us + o);
    }
  }
  for (int i = tid; i < 1024; i += 256) { cb[i] = 0.f; ho[i] = 0.f; }
  asm volatile("s_waitcnt vmcnt(0)" ::: "memory");
  __syncthreads();

  int m2 = wid >> 1, n2 = wid & 1;
  int kls = (lane >> 4) * 16;
  int j0 = n2 * 32 + (lane & 15);
  int bo0 = j0 * UROW + kls;
  int bo1 = bo0 + 16 * UROW;
  int b0i = (m2 * 32 + (lane & 15)) * 256 + (kls >> 3);  // u64 units (row = 256 u64)
  int b1i = b0i + 16 * 256;
  int ub = tid >> 2, uq = tid & 3;

  for (int t = 0; t < TT; ++t) {
    uint2 xg[4];
    {
      const char* xp = (const char*)xw + (((size_t)ub * TT + t) * FH + w * 64) * 2;
      #pragma unroll
      for (int g = 0; g < 4; ++g) xg[g] = *(const uint2*)(xp + (g * 16 + uq * 4) * 2);
    }
    unsigned long long mb = mask64[t];
    f32x4 a00 = {0.f,0.f,0.f,0.f}, a01 = {0.f,0.f,0.f,0.f};
    f32x4 a10 = {0.f,0.f,0.f,0.f}, a11 = {0.f,0.f,0.f,0.f};

    if (t > 0) {
      // every wave polls independently (no fence: data read coherently below)
      {
        const unsigned* fl = flags + (size_t)(t - 1) * 64;
        for (;;) {
          unsigned v = __hip_atomic_load(fl + lane, __ATOMIC_RELAXED, __HIP_MEMORY_SCOPE_AGENT);
          if (__all(v != 0)) break;
          __builtin_amdgcn_s_sleep(1);
        }
      }
      const unsigned long long* h64 = (const unsigned long long*)(hseq + (size_t)(t - 1) * 65536);
      HALF(0);
      HALF(16);
    }

    {
      int jb = n2 * 32 + (lane & 15);
      int rb = m2 * 32 + (lane >> 4) * 4;
      #pragma unroll
      for (int r = 0; r < 4; ++r) {
        zl[(rb + r) * 65 + jb]           = a00[r];
        zl[(rb + r) * 65 + jb + 16]      = a01[r];
        zl[(rb + 16 + r) * 65 + jb]      = a10[r];
        zl[(rb + 16 + r) * 65 + jb + 16] = a11[r];
      }
    }
    __syncthreads();

    {
      int jj0 = uq * 4;
      bool mk = (mb >> ub) & 1ull;
      unsigned long long pack = 0;
      float hv4[4];
      #pragma unroll
      for (int u = 0; u < 4; ++u) {
        int jj = jj0 + u;
        float zi = zl[ub * 65 + jj]      + get_bf_u2(xg[0], u);
        float zf = zl[ub * 65 + 16 + jj] + get_bf_u2(xg[1], u);
        float zg = zl[ub * 65 + 32 + jj] + get_bf_u2(xg[2], u);
        float zo = zl[ub * 65 + 48 + jj] + get_bf_u2(xg[3], u);
        float I = sigm(zi), F = sigm(zf), G = tanh_f(zg), O = sigm(zo);
        float cold = cb[ub * 16 + jj];
        float cn = F * cold + I * G;
        float hn = O * tanh_f(cn);
        if (!mk) { cn = cold; hn = ho[ub * 16 + jj]; }
        cb[ub * 16 + jj] = cn;
        ho[ub * 16 + jj] = hn;
        pack |= (unsigned long long)f2bf(hn) << (16 * u);
        hv4[u] = hn;
      }
      __hip_atomic_store(
        (unsigned long long*)(hseq + (size_t)t * 65536 + ub * 1024 + w * 16 + jj0),
        pack, __ATOMIC_RELAXED, __HIP_MEMORY_SCOPE_AGENT);
      if (t == TT - 1) {
        #pragma unroll
        for (int u = 0; u < 4; ++u) hfin[ub * 1024 + w * 16 + jj0 + u] = hv4[u];
      }
    }
    asm volatile("s_waitcnt vmcnt(0)" ::: "memory");
    __syncthreads();
    if (tid == 0)
      __hip_atomic_store(flags + (size_t)t * 64 + w, 1u, __ATOMIC_RELEASE, __HIP_MEMORY_SCOPE_AGENT);
  }
}

// ---------------- VAE head ----------------

__global__ void k_final(const float* __restrict__ hfin, const float* __restrict__ Wm,
                        const float* __restrict__ bm, const float* __restrict__ Wv,
                        const float* __restrict__ bv, const float* __restrict__ eps,
                        float* __restrict__ out) {
  int jb = blockIdx.x;
  int b = threadIdx.x & 63, u = threadIdx.x >> 6;
  int c0 = jb * 16 + u * 4;
  float am[4] = {0.f, 0.f, 0.f, 0.f};
  float av[4] = {0.f, 0.f, 0.f, 0.f};
  const float* hb = hfin + b * 1024;
  #pragma unroll 2
  for (int k = 0; k < 1024; ++k) {
    float hv = hb[k];
    float4 wm = *(const float4*)(Wm + (size_t)k * 1024 + c0);
    float4 wv = *(const float4*)(Wv + (size_t)k * 1024 + c0);
    am[0] += hv * wm.x; am[1] += hv * wm.y; am[2] += hv * wm.z; am[3] += hv * wm.w;
    av[0] += hv * wv.x; av[1] += hv * wv.y; av[2] += hv * wv.z; av[3] += hv * wv.w;
  }
  #pragma unroll
  for (int i = 0; i < 4; ++i) {
    int c = c0 + i;
    float mean = am[i] + bm[c];
    float lv = av[i] + bv[c];
    out[b * 1024 + c] = eps[b * 1024 + c] * __expf(0.5f * lv) + mean;
  }
}

// ---------------- launch ----------------

extern "C" void kernel_launch(void* const* d_in, const int* in_sizes, int n_in,
                              void* d_out, int out_size, void* d_ws, size_t ws_size,
                              hipStream_t stream) {
  const int*   tok = (const int*)d_in[0];
  const float* emb = (const float*)d_in[1];
  const float* W   = (const float*)d_in[2];
  const float* U   = (const float*)d_in[3];
  const float* bia = (const float*)d_in[4];
  const float* Wm  = (const float*)d_in[5];
  const float* bm  = (const float*)d_in[6];
  const float* Wv  = (const float*)d_in[7];
  const float* bv  = (const float*)d_in[8];
  const float* eps = (const float*)d_in[9];
  float* out = (float*)d_out;

  char* ws = (char*)d_ws;
  size_t off = 0;
  auto alloc = [&](size_t sz) { char* p = ws + off; off += (sz + 255) & ~(size_t)255; return p; };
  unsigned short* embb = (unsigned short*)alloc((size_t)VV * DD * 2);
  unsigned short* Wt   = (unsigned short*)alloc((size_t)FH * DD * 2);
  float*  bperm        = (float*)alloc((size_t)FH * 4);
  unsigned short* Uprep= (unsigned short*)alloc((size_t)64 * UBLK);
  unsigned short* xw   = (unsigned short*)alloc((size_t)BB * TT * FH * 2);
  unsigned short* hseq = (unsigned short*)alloc((size_t)TT * 131072);
  unsigned* flags      = (unsigned*)alloc((size_t)TT * 64 * 4);
  unsigned long long* mask64 = (unsigned long long*)alloc((size_t)TT * 8);
  float* hfin          = (float*)alloc((size_t)BB * HH * 4);
  (void)in_sizes; (void)n_in; (void)out_size; (void)ws_size;

  (void)hipMemsetAsync(flags, 0, (size_t)TT * 64 * 4, stream);
  k_cast_emb<<<8000, 256, 0, stream>>>(emb, embb);
  k_prep_w<<<4096, 128, 0, stream>>>(W, bia, Wt, bperm);
  k_prep_u<<<4096, 128, 0, stream>>>(U, Uprep);
  k_mask<<<1, 256, 0, stream>>>(tok, mask64);
  k_gemm_xw<<<4096, 256, 0, stream>>>(tok, embb, Wt, bperm, xw);
  (void)hipFuncSetAttribute((const void*)k_lstm, hipFuncAttributeMaxDynamicSharedMemorySize, LSTM_LDS);
  k_lstm<<<64, 256, LSTM_LDS, stream>>>(Uprep, xw, mask64, hseq, flags, hfin);
  k_final<<<64, 256, 0, stream>>>(hfin, Wm, bm, Wv, bv, eps, out);
}

// Round 6
// 3941.672 us; speedup vs baseline: 1.3752x; 1.3752x over previous
//
#include <hip/hip_runtime.h>
#include <stdint.h>

#define BB 64
#define TT 256
#define VV 32000
#define DD 512
#define HH 1024
#define FH 4096

// Padded U row stride: 2048 data bytes + 16 pad = 2064 (4-bank shift per row)
#define UROW 2064
#define UBLK (64 * UROW)   // 132096 bytes per WG

typedef float f32x4 __attribute__((ext_vector_type(4)));
typedef __bf16 bf16x8 __attribute__((ext_vector_type(8)));

typedef __attribute__((address_space(1))) void void_g;
typedef __attribute__((address_space(3))) void void_l;

static __device__ __forceinline__ void gload_lds16(const void* g, void* l) {
  __builtin_amdgcn_global_load_lds((const void_g*)g, (void_l*)l, 16, 0, 0);
}

static __device__ __forceinline__ unsigned short f2bf(float f) {
  union { float f; unsigned u; } x; x.f = f;
  unsigned r = x.u + 0x7FFFu + ((x.u >> 16) & 1u);
  return (unsigned short)(r >> 16);
}
static __device__ __forceinline__ float bf2f(unsigned short s) {
  union { unsigned u; float f; } x; x.u = ((unsigned)s) << 16;
  return x.f;
}
static __device__ __forceinline__ bf16x8 as_bf16x8(uint4 v) {
  union { uint4 u; bf16x8 b; } x; x.u = v; return x.b;
}
static __device__ __forceinline__ float sigm(float x) {
  return 1.f / (1.f + __expf(-x));
}
static __device__ __forceinline__ float tanh_f(float x) {
  x = fminf(15.f, fmaxf(-15.f, x));
  float e = __expf(2.f * x);
  return (e - 1.f) / (e + 1.f);
}
static __device__ __forceinline__ float get_bf_u2(uint2 v, int u) {
  unsigned r = (u < 2) ? v.x : v.y;
  return bf2f((unsigned short)((u & 1) ? (r >> 16) : (r & 0xFFFFu)));
}

// ---------------- prep kernels ----------------

__global__ void k_cast_emb(const float* __restrict__ src, unsigned short* __restrict__ dst) {
  size_t i = ((size_t)blockIdx.x * 256 + threadIdx.x) * 8;
  float4 a = *(const float4*)(src + i);
  float4 b = *(const float4*)(src + i + 4);
  uint4 o;
  o.x = (unsigned)f2bf(a.x) | ((unsigned)f2bf(a.y) << 16);
  o.y = (unsigned)f2bf(a.z) | ((unsigned)f2bf(a.w) << 16);
  o.z = (unsigned)f2bf(b.x) | ((unsigned)f2bf(b.y) << 16);
  o.w = (unsigned)f2bf(b.z) | ((unsigned)f2bf(b.w) << 16);
  *(uint4*)(dst + i) = o;
}

// W_t[n'][k] bf16 (transposed, column-permuted), b_perm[n'] f32.
// n' = w*64 + g*16 + jj  <->  n = g*1024 + w*16 + jj
__global__ void k_prep_w(const float* __restrict__ Wsrc, const float* __restrict__ bsrc,
                         unsigned short* __restrict__ Wt, float* __restrict__ bperm) {
  int np = blockIdx.x;
  int w = np >> 6, r = np & 63, g = r >> 4, jj = r & 15;
  int n = g * 1024 + w * 16 + jj;
  int k0 = threadIdx.x * 4;
  unsigned short q0 = f2bf(Wsrc[(size_t)(k0 + 0) * FH + n]);
  unsigned short q1 = f2bf(Wsrc[(size_t)(k0 + 1) * FH + n]);
  unsigned short q2 = f2bf(Wsrc[(size_t)(k0 + 2) * FH + n]);
  unsigned short q3 = f2bf(Wsrc[(size_t)(k0 + 3) * FH + n]);
  uint2 o;
  o.x = (unsigned)q0 | ((unsigned)q1 << 16);
  o.y = (unsigned)q2 | ((unsigned)q3 << 16);
  *(uint2*)((char*)Wt + (size_t)np * 1024 + (size_t)k0 * 2) = o;
  if (threadIdx.x == 0) bperm[np] = bsrc[n];
}

// U_prep: per WG w, padded-linear LDS image: row j (64 rows) at j*UROW,
// 2048 bytes of bf16 U[n(j,w)][k] + 16 pad bytes (zeroed).
__global__ void k_prep_u(const float* __restrict__ Usrc, unsigned short* __restrict__ Uprep) {
  int bid = blockIdx.x;            // 0..4095 = w*64 + j
  int j = bid & 63;
  int w = bid >> 6;
  int g = j >> 4, jj = j & 15;
  int n = g * 1024 + w * 16 + jj;
  int k0 = threadIdx.x * 8;
  unsigned p[4];
  #pragma unroll
  for (int h = 0; h < 4; ++h) {
    unsigned short e0 = f2bf(Usrc[(size_t)(k0 + 2 * h) * FH + n]);
    unsigned short e1 = f2bf(Usrc[(size_t)(k0 + 2 * h + 1) * FH + n]);
    p[h] = (unsigned)e0 | ((unsigned)e1 << 16);
  }
  uint4 o; o.x = p[0]; o.y = p[1]; o.z = p[2]; o.w = p[3];
  char* dst = (char*)Uprep + (size_t)w * UBLK + (size_t)j * UROW;
  *(uint4*)(dst + threadIdx.x * 16) = o;
  if (threadIdx.x == 0) { uint4 z = {0, 0, 0, 0}; *(uint4*)(dst + 2048) = z; }
}

__global__ void k_mask(const int* __restrict__ tok, unsigned long long* __restrict__ mask64) {
  int t = threadIdx.x;
  unsigned long long m = 0;
  for (int b = 0; b < BB; ++b)
    m |= (unsigned long long)(tok[b * TT + t] != 0) << b;
  mask64[t] = m;
}

// ---------------- xW GEMM (gather fused) ----------------

__launch_bounds__(256)
__global__ void k_gemm_xw(const int* __restrict__ tok, const unsigned short* __restrict__ embb,
                          const unsigned short* __restrict__ Wt, const float* __restrict__ bperm,
                          unsigned short* __restrict__ xw) {
  __shared__ char As[16384];
  __shared__ char Bs[16384];
  __shared__ int toks[128];
  int tid = threadIdx.x, lane = tid & 63, wid = tid >> 6;
  int bm = blockIdx.x >> 5, bn = blockIdx.x & 31;
  if (tid < 128) toks[tid] = tok[bm * 128 + tid];
  int wm = wid >> 1, wn = wid & 1;
  f32x4 vz = {0.f, 0.f, 0.f, 0.f};
  f32x4 acc[4][4];
  #pragma unroll
  for (int i = 0; i < 4; ++i)
    #pragma unroll
    for (int j = 0; j < 4; ++j) acc[i][j] = vz;

  int kls = (lane >> 4) * 16;
  for (int ks = 0; ks < 8; ++ks) {
    __syncthreads();
    #pragma unroll
    for (int c = 0; c < 4; ++c) {
      int o = wid * 4096 + c * 1024 + lane * 16;
      int m = o >> 7, kl = o & 127;
      const char* ga = (const char*)embb + (size_t)toks[m] * 1024 + ks * 128 + (kl ^ ((m & 7) << 4));
      gload_lds16(ga, As + o);
      const char* gb = (const char*)Wt + (size_t)(bn * 128 + m) * 1024 + ks * 128 + (kl ^ ((m & 7) << 4));
      gload_lds16(gb, Bs + o);
    }
    asm volatile("s_waitcnt vmcnt(0)" ::: "memory");
    __syncthreads();
    #pragma unroll
    for (int tk = 0; tk < 2; ++tk) {
      bf16x8 af[4], bf[4];
      int kb = tk * 64 + kls;
      #pragma unroll
      for (int mt = 0; mt < 4; ++mt) {
        int m = wm * 64 + mt * 16 + (lane & 15);
        af[mt] = *(const bf16x8*)(As + m * 128 + (kb ^ ((m & 7) << 4)));
      }
      #pragma unroll
      for (int nt = 0; nt < 4; ++nt) {
        int n = wn * 64 + nt * 16 + (lane & 15);
        bf[nt] = *(const bf16x8*)(Bs + n * 128 + (kb ^ ((n & 7) << 4)));
      }
      #pragma unroll
      for (int mt = 0; mt < 4; ++mt)
        #pragma unroll
        for (int nt = 0; nt < 4; ++nt)
          acc[mt][nt] = __builtin_amdgcn_mfma_f32_16x16x32_bf16(af[mt], bf[nt], acc[mt][nt], 0, 0, 0);
    }
  }
  #pragma unroll
  for (int nt = 0; nt < 4; ++nt) {
    int col = bn * 128 + wn * 64 + nt * 16 + (lane & 15);
    float bias = bperm[col];
    #pragma unroll
    for (int mt = 0; mt < 4; ++mt) {
      #pragma unroll
      for (int r = 0; r < 4; ++r) {
        int row = bm * 128 + wm * 64 + mt * 16 + (lane >> 4) * 4 + r;
        xw[(size_t)row * FH + col] = f2bf(acc[mt][nt][r] + bias);
      }
    }
  }
}

// ---------------- persistent LSTM scan ----------------
// 64 WGs, WG w owns h cols [16w,16w+16). U resident in LDS (padded rows).
// h broadcast via per-step monotonic global buffers:
//   producers: relaxed agent atomic stores (write-through LLC) + vmcnt(0) + release flag
//   consumers: flag poll, then PLAIN cached loads. Safe because step regions are
//   first-touch (never cached before producers wrote: dispatch-start acquire
//   invalidated L1/L2, addresses monotonic) -> L2 miss -> fresh LLC data, and
//   the 8 WGs of an XCD share the L2-filled lines.

#define LSTM_LDS (UBLK + 16640 + 4096 + 4096)

// One K-half: 32 plain uint4 loads (compiler-pipelined), then 16x4 MFMAs
#define HALF(TKB) do { \
  uint4 ha[16], hbv[16]; \
  _Pragma("unroll") \
  for (int tk = 0; tk < 16; ++tk) { \
    ha[tk]  = *(const uint4*)(hp + b0B + ((TKB) + tk) * 64); \
    hbv[tk] = *(const uint4*)(hp + b1B + ((TKB) + tk) * 64); \
  } \
  _Pragma("unroll") \
  for (int tk = 0; tk < 16; ++tk) { \
    bf16x8 b0_ = *(const bf16x8*)(Us + bo0 + ((TKB) + tk) * 64); \
    bf16x8 b1_ = *(const bf16x8*)(Us + bo1 + ((TKB) + tk) * 64); \
    bf16x8 a0_ = as_bf16x8(ha[tk]); \
    bf16x8 a1_ = as_bf16x8(hbv[tk]); \
    a00 = __builtin_amdgcn_mfma_f32_16x16x32_bf16(a0_, b0_, a00, 0, 0, 0); \
    a01 = __builtin_amdgcn_mfma_f32_16x16x32_bf16(a0_, b1_, a01, 0, 0, 0); \
    a10 = __builtin_amdgcn_mfma_f32_16x16x32_bf16(a1_, b0_, a10, 0, 0, 0); \
    a11 = __builtin_amdgcn_mfma_f32_16x16x32_bf16(a1_, b1_, a11, 0, 0, 0); \
  } \
} while (0)

__launch_bounds__(256, 1)
__global__ void k_lstm(const unsigned short* __restrict__ Uprep, const unsigned short* __restrict__ xw,
                       const unsigned long long* __restrict__ mask64,
                       unsigned short* __restrict__ hseq, unsigned* __restrict__ flags,
                       float* __restrict__ hfin) {
  extern __shared__ char smem[];
  char* Us = smem;
  float* zl = (float*)(smem + UBLK);                 // [64][65] f32
  float* cb = (float*)(smem + UBLK + 16640);         // [64][16] f32
  float* ho = (float*)(smem + UBLK + 16640 + 4096);  // [64][16] f32
  int tid = threadIdx.x, lane = tid & 63, wid = tid >> 6;
  int w = blockIdx.x;

  {
    const char* src = (const char*)Uprep + (size_t)w * UBLK;
    #pragma unroll
    for (int c = 0; c < 32; ++c) {
      int o = c * 4096 + tid * 16;
      gload_lds16(src + o, Us + o);
    }
    if (wid == 0) {  // tail: 1024 bytes
      int o = 131072 + lane * 16;
      gload_lds16(src + o, Us + o);
    }
  }
  for (int i = tid; i < 1024; i += 256) { cb[i] = 0.f; ho[i] = 0.f; }
  asm volatile("s_waitcnt vmcnt(0)" ::: "memory");
  __syncthreads();

  int m2 = wid >> 1, n2 = wid & 1;
  int kls = (lane >> 4) * 16;
  int j0 = n2 * 32 + (lane & 15);
  int bo0 = j0 * UROW + kls;
  int bo1 = bo0 + 16 * UROW;
  int b0B = (m2 * 32 + (lane & 15)) * 2048 + kls;  // byte offset, row = 2048 B
  int b1B = b0B + 16 * 2048;
  int ub = tid >> 2, uq = tid & 3;

  for (int t = 0; t < TT; ++t) {
    uint2 xg[4];
    {
      const char* xp = (const char*)xw + (((size_t)ub * TT + t) * FH + w * 64) * 2;
      #pragma unroll
      for (int g = 0; g < 4; ++g) xg[g] = *(const uint2*)(xp + (g * 16 + uq * 4) * 2);
    }
    unsigned long long mb = mask64[t];
    f32x4 a00 = {0.f,0.f,0.f,0.f}, a01 = {0.f,0.f,0.f,0.f};
    f32x4 a10 = {0.f,0.f,0.f,0.f}, a11 = {0.f,0.f,0.f,0.f};

    if (t > 0) {
      // every wave polls independently
      {
        const unsigned* fl = flags + (size_t)(t - 1) * 64;
        for (;;) {
          unsigned v = __hip_atomic_load(fl + lane, __ATOMIC_RELAXED, __HIP_MEMORY_SCOPE_AGENT);
          if (__all(v != 0)) break;
          __builtin_amdgcn_s_sleep(1);
        }
      }
      // compiler barrier: keep the plain h loads below the poll (HW issues in order)
      asm volatile("" ::: "memory");
      const char* hp = (const char*)hseq + (size_t)(t - 1) * 131072;
      HALF(0);
      HALF(16);
    }

    {
      int jb = n2 * 32 + (lane & 15);
      int rb = m2 * 32 + (lane >> 4) * 4;
      #pragma unroll
      for (int r = 0; r < 4; ++r) {
        zl[(rb + r) * 65 + jb]           = a00[r];
        zl[(rb + r) * 65 + jb + 16]      = a01[r];
        zl[(rb + 16 + r) * 65 + jb]      = a10[r];
        zl[(rb + 16 + r) * 65 + jb + 16] = a11[r];
      }
    }
    __syncthreads();

    {
      int jj0 = uq * 4;
      bool mk = (mb >> ub) & 1ull;
      unsigned long long pack = 0;
      float hv4[4];
      #pragma unroll
      for (int u = 0; u < 4; ++u) {
        int jj = jj0 + u;
        float zi = zl[ub * 65 + jj]      + get_bf_u2(xg[0], u);
        float zf = zl[ub * 65 + 16 + jj] + get_bf_u2(xg[1], u);
        float zg = zl[ub * 65 + 32 + jj] + get_bf_u2(xg[2], u);
        float zo = zl[ub * 65 + 48 + jj] + get_bf_u2(xg[3], u);
        float I = sigm(zi), F = sigm(zf), G = tanh_f(zg), O = sigm(zo);
        float cold = cb[ub * 16 + jj];
        float cn = F * cold + I * G;
        float hn = O * tanh_f(cn);
        if (!mk) { cn = cold; hn = ho[ub * 16 + jj]; }
        cb[ub * 16 + jj] = cn;
        ho[ub * 16 + jj] = hn;
        pack |= (unsigned long long)f2bf(hn) << (16 * u);
        hv4[u] = hn;
      }
      __hip_atomic_store(
        (unsigned long long*)(hseq + (size_t)t * 65536 + ub * 1024 + w * 16 + jj0),
        pack, __ATOMIC_RELAXED, __HIP_MEMORY_SCOPE_AGENT);
      if (t == TT - 1) {
        #pragma unroll
        for (int u = 0; u < 4; ++u) hfin[ub * 1024 + w * 16 + jj0 + u] = hv4[u];
      }
    }
    asm volatile("s_waitcnt vmcnt(0)" ::: "memory");
    __syncthreads();
    if (tid == 0)
      __hip_atomic_store(flags + (size_t)t * 64 + w, 1u, __ATOMIC_RELEASE, __HIP_MEMORY_SCOPE_AGENT);
  }
}

// ---------------- VAE head ----------------

__global__ void k_final(const float* __restrict__ hfin, const float* __restrict__ Wm,
                        const float* __restrict__ bm, const float* __restrict__ Wv,
                        const float* __restrict__ bv, const float* __restrict__ eps,
                        float* __restrict__ out) {
  int jb = blockIdx.x;
  int b = threadIdx.x & 63, u = threadIdx.x >> 6;
  int c0 = jb * 16 + u * 4;
  float am[4] = {0.f, 0.f, 0.f, 0.f};
  float av[4] = {0.f, 0.f, 0.f, 0.f};
  const float* hb = hfin + b * 1024;
  #pragma unroll 2
  for (int k = 0; k < 1024; ++k) {
    float hv = hb[k];
    float4 wm = *(const float4*)(Wm + (size_t)k * 1024 + c0);
    float4 wv = *(const float4*)(Wv + (size_t)k * 1024 + c0);
    am[0] += hv * wm.x; am[1] += hv * wm.y; am[2] += hv * wm.z; am[3] += hv * wm.w;
    av[0] += hv * wv.x; av[1] += hv * wv.y; av[2] += hv * wv.z; av[3] += hv * wv.w;
  }
  #pragma unroll
  for (int i = 0; i < 4; ++i) {
    int c = c0 + i;
    float mean = am[i] + bm[c];
    float lv = av[i] + bv[c];
    out[b * 1024 + c] = eps[b * 1024 + c] * __expf(0.5f * lv) + mean;
  }
}

// ---------------- launch ----------------

extern "C" void kernel_launch(void* const* d_in, const int* in_sizes, int n_in,
                              void* d_out, int out_size, void* d_ws, size_t ws_size,
                              hipStream_t stream) {
  const int*   tok = (const int*)d_in[0];
  const float* emb = (const float*)d_in[1];
  const float* W   = (const float*)d_in[2];
  const float* U   = (const float*)d_in[3];
  const float* bia = (const float*)d_in[4];
  const float* Wm  = (const float*)d_in[5];
  const float* bm  = (const float*)d_in[6];
  const float* Wv  = (const float*)d_in[7];
  const float* bv  = (const float*)d_in[8];
  const float* eps = (const float*)d_in[9];
  float* out = (float*)d_out;

  char* ws = (char*)d_ws;
  size_t off = 0;
  auto alloc = [&](size_t sz) { char* p = ws + off; off += (sz + 255) & ~(size_t)255; return p; };
  unsigned short* embb = (unsigned short*)alloc((size_t)VV * DD * 2);
  unsigned short* Wt   = (unsigned short*)alloc((size_t)FH * DD * 2);
  float*  bperm        = (float*)alloc((size_t)FH * 4);
  unsigned short* Uprep= (unsigned short*)alloc((size_t)64 * UBLK);
  unsigned short* xw   = (unsigned short*)alloc((size_t)BB * TT * FH * 2);
  unsigned short* hseq = (unsigned short*)alloc((size_t)TT * 131072);
  unsigned* flags      = (unsigned*)alloc((size_t)TT * 64 * 4);
  unsigned long long* mask64 = (unsigned long long*)alloc((size_t)TT * 8);
  float* hfin          = (float*)alloc((size_t)BB * HH * 4);
  (void)in_sizes; (void)n_in; (void)out_size; (void)ws_size;

  (void)hipMemsetAsync(flags, 0, (size_t)TT * 64 * 4, stream);
  k_cast_emb<<<8000, 256, 0, stream>>>(emb, embb);
  k_prep_w<<<4096, 128, 0, stream>>>(W, bia, Wt, bperm);
  k_prep_u<<<4096, 128, 0, stream>>>(U, Uprep);
  k_mask<<<1, 256, 0, stream>>>(tok, mask64);
  k_gemm_xw<<<4096, 256, 0, stream>>>(tok, embb, Wt, bperm, xw);
  (void)hipFuncSetAttribute((const void*)k_lstm, hipFuncAttributeMaxDynamicSharedMemorySize, LSTM_LDS);
  k_lstm<<<64, 256, LSTM_LDS, stream>>>(Uprep, xw, mask64, hseq, flags, hfin);
  k_final<<<64, 256, 0, stream>>>(hfin, Wm, bm, Wv, bv, eps, out);
}

// Round 7
// 3525.674 us; speedup vs baseline: 1.5374x; 1.1180x over previous
//
#include <hip/hip_runtime.h>
#include <stdint.h>

#define BB 64
#define TT 256
#define VV 32000
#define DD 512
#define HH 1024
#define FH 4096

// Padded U row stride: 2048 data bytes + 16 pad = 2064 (4-bank shift per row)
#define UROW 2064
#define UBLK (64 * UROW)   // 132096 bytes per WG

#define FLAG_PAIR 0x0000000100000001ULL

typedef float f32x4 __attribute__((ext_vector_type(4)));
typedef __bf16 bf16x8 __attribute__((ext_vector_type(8)));

typedef __attribute__((address_space(1))) void void_g;
typedef __attribute__((address_space(3))) void void_l;

static __device__ __forceinline__ void gload_lds16(const void* g, void* l) {
  __builtin_amdgcn_global_load_lds((const void_g*)g, (void_l*)l, 16, 0, 0);
}

static __device__ __forceinline__ unsigned short f2bf(float f) {
  union { float f; unsigned u; } x; x.f = f;
  unsigned r = x.u + 0x7FFFu + ((x.u >> 16) & 1u);
  return (unsigned short)(r >> 16);
}
static __device__ __forceinline__ float bf2f(unsigned short s) {
  union { unsigned u; float f; } x; x.u = ((unsigned)s) << 16;
  return x.f;
}
static __device__ __forceinline__ bf16x8 as_bf16x8(uint4 v) {
  union { uint4 u; bf16x8 b; } x; x.u = v; return x.b;
}
static __device__ __forceinline__ float sigm(float x) {
  return 1.f / (1.f + __expf(-x));
}
static __device__ __forceinline__ float tanh_f(float x) {
  x = fminf(15.f, fmaxf(-15.f, x));
  float e = __expf(2.f * x);
  return (e - 1.f) / (e + 1.f);
}
static __device__ __forceinline__ float get_bf_u2(uint2 v, int u) {
  unsigned r = (u < 2) ? v.x : v.y;
  return bf2f((unsigned short)((u & 1) ? (r >> 16) : (r & 0xFFFFu)));
}

// ---------------- prep kernels ----------------

__global__ void k_cast_emb(const float* __restrict__ src, unsigned short* __restrict__ dst) {
  size_t i = ((size_t)blockIdx.x * 256 + threadIdx.x) * 8;
  float4 a = *(const float4*)(src + i);
  float4 b = *(const float4*)(src + i + 4);
  uint4 o;
  o.x = (unsigned)f2bf(a.x) | ((unsigned)f2bf(a.y) << 16);
  o.y = (unsigned)f2bf(a.z) | ((unsigned)f2bf(a.w) << 16);
  o.z = (unsigned)f2bf(b.x) | ((unsigned)f2bf(b.y) << 16);
  o.w = (unsigned)f2bf(b.z) | ((unsigned)f2bf(b.w) << 16);
  *(uint4*)(dst + i) = o;
}

// W_t[n'][k] bf16 (transposed, column-permuted), b_perm[n'] f32.
// n' = w*64 + g*16 + jj  <->  n = g*1024 + w*16 + jj
__global__ void k_prep_w(const float* __restrict__ Wsrc, const float* __restrict__ bsrc,
                         unsigned short* __restrict__ Wt, float* __restrict__ bperm) {
  int np = blockIdx.x;
  int w = np >> 6, r = np & 63, g = r >> 4, jj = r & 15;
  int n = g * 1024 + w * 16 + jj;
  int k0 = threadIdx.x * 4;
  unsigned short q0 = f2bf(Wsrc[(size_t)(k0 + 0) * FH + n]);
  unsigned short q1 = f2bf(Wsrc[(size_t)(k0 + 1) * FH + n]);
  unsigned short q2 = f2bf(Wsrc[(size_t)(k0 + 2) * FH + n]);
  unsigned short q3 = f2bf(Wsrc[(size_t)(k0 + 3) * FH + n]);
  uint2 o;
  o.x = (unsigned)q0 | ((unsigned)q1 << 16);
  o.y = (unsigned)q2 | ((unsigned)q3 << 16);
  *(uint2*)((char*)Wt + (size_t)np * 1024 + (size_t)k0 * 2) = o;
  if (threadIdx.x == 0) bperm[np] = bsrc[n];
}

// U_prep: per WG w, padded-linear LDS image: row j (64 rows) at j*UROW,
// 2048 bytes of bf16 U[n(j,w)][k] + 16 pad bytes (zeroed).
__global__ void k_prep_u(const float* __restrict__ Usrc, unsigned short* __restrict__ Uprep) {
  int bid = blockIdx.x;            // 0..4095 = w*64 + j
  int j = bid & 63;
  int w = bid >> 6;
  int g = j >> 4, jj = j & 15;
  int n = g * 1024 + w * 16 + jj;
  int k0 = threadIdx.x * 8;
  unsigned p[4];
  #pragma unroll
  for (int h = 0; h < 4; ++h) {
    unsigned short e0 = f2bf(Usrc[(size_t)(k0 + 2 * h) * FH + n]);
    unsigned short e1 = f2bf(Usrc[(size_t)(k0 + 2 * h + 1) * FH + n]);
    p[h] = (unsigned)e0 | ((unsigned)e1 << 16);
  }
  uint4 o; o.x = p[0]; o.y = p[1]; o.z = p[2]; o.w = p[3];
  char* dst = (char*)Uprep + (size_t)w * UBLK + (size_t)j * UROW;
  *(uint4*)(dst + threadIdx.x * 16) = o;
  if (threadIdx.x == 0) { uint4 z = {0, 0, 0, 0}; *(uint4*)(dst + 2048) = z; }
}

__global__ void k_mask(const int* __restrict__ tok, unsigned long long* __restrict__ mask64) {
  int t = threadIdx.x;
  unsigned long long m = 0;
  for (int b = 0; b < BB; ++b)
    m |= (unsigned long long)(tok[b * TT + t] != 0) << b;
  mask64[t] = m;
}

// ---------------- xW GEMM (gather fused) ----------------

__launch_bounds__(256)
__global__ void k_gemm_xw(const int* __restrict__ tok, const unsigned short* __restrict__ embb,
                          const unsigned short* __restrict__ Wt, const float* __restrict__ bperm,
                          unsigned short* __restrict__ xw) {
  __shared__ char As[16384];
  __shared__ char Bs[16384];
  __shared__ int toks[128];
  int tid = threadIdx.x, lane = tid & 63, wid = tid >> 6;
  int bm = blockIdx.x >> 5, bn = blockIdx.x & 31;
  if (tid < 128) toks[tid] = tok[bm * 128 + tid];
  int wm = wid >> 1, wn = wid & 1;
  f32x4 vz = {0.f, 0.f, 0.f, 0.f};
  f32x4 acc[4][4];
  #pragma unroll
  for (int i = 0; i < 4; ++i)
    #pragma unroll
    for (int j = 0; j < 4; ++j) acc[i][j] = vz;

  int kls = (lane >> 4) * 16;
  for (int ks = 0; ks < 8; ++ks) {
    __syncthreads();
    #pragma unroll
    for (int c = 0; c < 4; ++c) {
      int o = wid * 4096 + c * 1024 + lane * 16;
      int m = o >> 7, kl = o & 127;
      const char* ga = (const char*)embb + (size_t)toks[m] * 1024 + ks * 128 + (kl ^ ((m & 7) << 4));
      gload_lds16(ga, As + o);
      const char* gb = (const char*)Wt + (size_t)(bn * 128 + m) * 1024 + ks * 128 + (kl ^ ((m & 7) << 4));
      gload_lds16(gb, Bs + o);
    }
    asm volatile("s_waitcnt vmcnt(0)" ::: "memory");
    __syncthreads();
    #pragma unroll
    for (int tk = 0; tk < 2; ++tk) {
      bf16x8 af[4], bf[4];
      int kb = tk * 64 + kls;
      #pragma unroll
      for (int mt = 0; mt < 4; ++mt) {
        int m = wm * 64 + mt * 16 + (lane & 15);
        af[mt] = *(const bf16x8*)(As + m * 128 + (kb ^ ((m & 7) << 4)));
      }
      #pragma unroll
      for (int nt = 0; nt < 4; ++nt) {
        int n = wn * 64 + nt * 16 + (lane & 15);
        bf[nt] = *(const bf16x8*)(Bs + n * 128 + (kb ^ ((n & 7) << 4)));
      }
      #pragma unroll
      for (int mt = 0; mt < 4; ++mt)
        #pragma unroll
        for (int nt = 0; nt < 4; ++nt)
          acc[mt][nt] = __builtin_amdgcn_mfma_f32_16x16x32_bf16(af[mt], bf[nt], acc[mt][nt], 0, 0, 0);
    }
  }
  #pragma unroll
  for (int nt = 0; nt < 4; ++nt) {
    int col = bn * 128 + wn * 64 + nt * 16 + (lane & 15);
    float bias = bperm[col];
    #pragma unroll
    for (int mt = 0; mt < 4; ++mt) {
      #pragma unroll
      for (int r = 0; r < 4; ++r) {
        int row = bm * 128 + wm * 64 + mt * 16 + (lane >> 4) * 4 + r;
        xw[(size_t)row * FH + col] = f2bf(acc[mt][nt][r] + bias);
      }
    }
  }
}

// ---------------- persistent LSTM scan ----------------
// 64 WGs, WG w owns h cols [16w,16w+16). U resident in LDS (padded rows).
// h broadcast via per-step monotonic global buffers:
//   producers: relaxed agent atomic stores (write-through LLC), per-wave
//              vmcnt(0) drain, then per-wave RELAXED flag (no release -> no
//              L2 writeback maintenance op on the critical path).
//   consumers: per-wave split poll (producers 0..31, then 32..63), plain
//              cached loads (first-touch regions; dispatch-start acquire
//              invalidated L1/L2 so no stale lines possible).

#define LSTM_LDS (UBLK + 16640 + 4096 + 4096)

// One K-half: 32 plain uint4 loads (compiler-pipelined), then 16x4 MFMAs
#define HALF(TKB) do { \
  uint4 ha[16], hbv[16]; \
  _Pragma("unroll") \
  for (int tk = 0; tk < 16; ++tk) { \
    ha[tk]  = *(const uint4*)(hp + b0B + ((TKB) + tk) * 64); \
    hbv[tk] = *(const uint4*)(hp + b1B + ((TKB) + tk) * 64); \
  } \
  _Pragma("unroll") \
  for (int tk = 0; tk < 16; ++tk) { \
    bf16x8 b0_ = *(const bf16x8*)(Us + bo0 + ((TKB) + tk) * 64); \
    bf16x8 b1_ = *(const bf16x8*)(Us + bo1 + ((TKB) + tk) * 64); \
    bf16x8 a0_ = as_bf16x8(ha[tk]); \
    bf16x8 a1_ = as_bf16x8(hbv[tk]); \
    a00 = __builtin_amdgcn_mfma_f32_16x16x32_bf16(a0_, b0_, a00, 0, 0, 0); \
    a01 = __builtin_amdgcn_mfma_f32_16x16x32_bf16(a0_, b1_, a01, 0, 0, 0); \
    a10 = __builtin_amdgcn_mfma_f32_16x16x32_bf16(a1_, b0_, a10, 0, 0, 0); \
    a11 = __builtin_amdgcn_mfma_f32_16x16x32_bf16(a1_, b1_, a11, 0, 0, 0); \
  } \
} while (0)

// Per-wave poll of 64 flag-pairs (u64 each == two u32 flags)
#define POLL(PBASE) do { \
  for (;;) { \
    unsigned long long v_ = __hip_atomic_load((PBASE) + lane, __ATOMIC_RELAXED, __HIP_MEMORY_SCOPE_AGENT); \
    if (__all(v_ == FLAG_PAIR)) break; \
    __builtin_amdgcn_s_sleep(1); \
  } \
  asm volatile("" ::: "memory"); \
} while (0)

__launch_bounds__(256, 1)
__global__ void k_lstm(const unsigned short* __restrict__ Uprep, const unsigned short* __restrict__ xw,
                       const unsigned long long* __restrict__ mask64,
                       unsigned short* __restrict__ hseq, unsigned* __restrict__ flags,
                       float* __restrict__ hfin) {
  extern __shared__ char smem[];
  char* Us = smem;
  float* zl = (float*)(smem + UBLK);                 // [64][65] f32
  float* cb = (float*)(smem + UBLK + 16640);         // [64][16] f32
  float* ho = (float*)(smem + UBLK + 16640 + 4096);  // [64][16] f32
  int tid = threadIdx.x, lane = tid & 63, wid = tid >> 6;
  int w = blockIdx.x;

  {
    const char* src = (const char*)Uprep + (size_t)w * UBLK;
    #pragma unroll
    for (int c = 0; c < 32; ++c) {
      int o = c * 4096 + tid * 16;
      gload_lds16(src + o, Us + o);
    }
    if (wid == 0) {  // tail: 1024 bytes
      int o = 131072 + lane * 16;
      gload_lds16(src + o, Us + o);
    }
  }
  for (int i = tid; i < 1024; i += 256) { cb[i] = 0.f; ho[i] = 0.f; }
  asm volatile("s_waitcnt vmcnt(0)" ::: "memory");
  __syncthreads();

  int m2 = wid >> 1, n2 = wid & 1;
  int kls = (lane >> 4) * 16;
  int j0 = n2 * 32 + (lane & 15);
  int bo0 = j0 * UROW + kls;
  int bo1 = bo0 + 16 * UROW;
  int b0B = (m2 * 32 + (lane & 15)) * 2048 + kls;  // byte offset, row = 2048 B
  int b1B = b0B + 16 * 2048;
  int ub = tid >> 2, uq = tid & 3;

  for (int t = 0; t < TT; ++t) {
    uint2 xg[4];
    {
      const char* xp = (const char*)xw + (((size_t)ub * TT + t) * FH + w * 64) * 2;
      #pragma unroll
      for (int g = 0; g < 4; ++g) xg[g] = *(const uint2*)(xp + (g * 16 + uq * 4) * 2);
    }
    unsigned long long mb = mask64[t];
    f32x4 a00 = {0.f,0.f,0.f,0.f}, a01 = {0.f,0.f,0.f,0.f};
    f32x4 a10 = {0.f,0.f,0.f,0.f}, a11 = {0.f,0.f,0.f,0.f};

    if (t > 0) {
      const unsigned long long* f64 =
          (const unsigned long long*)flags + (size_t)(t - 1) * 128;
      const char* hp = (const char*)hseq + (size_t)(t - 1) * 131072;
      POLL(f64);        // producers 0..31 (h cols 0..511 = K bytes 0..1023)
      HALF(0);
      POLL(f64 + 64);   // producers 32..63
      HALF(16);
    }

    {
      int jb = n2 * 32 + (lane & 15);
      int rb = m2 * 32 + (lane >> 4) * 4;
      #pragma unroll
      for (int r = 0; r < 4; ++r) {
        zl[(rb + r) * 65 + jb]           = a00[r];
        zl[(rb + r) * 65 + jb + 16]      = a01[r];
        zl[(rb + 16 + r) * 65 + jb]      = a10[r];
        zl[(rb + 16 + r) * 65 + jb + 16] = a11[r];
      }
    }
    __syncthreads();

    {
      int jj0 = uq * 4;
      bool mk = (mb >> ub) & 1ull;
      unsigned long long pack = 0;
      float hv4[4];
      #pragma unroll
      for (int u = 0; u < 4; ++u) {
        int jj = jj0 + u;
        float zi = zl[ub * 65 + jj]      + get_bf_u2(xg[0], u);
        float zf = zl[ub * 65 + 16 + jj] + get_bf_u2(xg[1], u);
        float zg = zl[ub * 65 + 32 + jj] + get_bf_u2(xg[2], u);
        float zo = zl[ub * 65 + 48 + jj] + get_bf_u2(xg[3], u);
        float I = sigm(zi), F = sigm(zf), G = tanh_f(zg), O = sigm(zo);
        float cold = cb[ub * 16 + jj];
        float cn = F * cold + I * G;
        float hn = O * tanh_f(cn);
        if (!mk) { cn = cold; hn = ho[ub * 16 + jj]; }
        cb[ub * 16 + jj] = cn;
        ho[ub * 16 + jj] = hn;
        pack |= (unsigned long long)f2bf(hn) << (16 * u);
        hv4[u] = hn;
      }
      __hip_atomic_store(
        (unsigned long long*)(hseq + (size_t)t * 65536 + ub * 1024 + w * 16 + jj0),
        pack, __ATOMIC_RELAXED, __HIP_MEMORY_SCOPE_AGENT);
      if (t == TT - 1) {
        #pragma unroll
        for (int u = 0; u < 4; ++u) hfin[ub * 1024 + w * 16 + jj0 + u] = hv4[u];
      }
    }
    // per-wave drain + per-wave relaxed flag (no release -> no L2 maintenance;
    // ordering: vmcnt(0) guarantees this wave's h stores reached the LLC)
    asm volatile("s_waitcnt vmcnt(0)" ::: "memory");
    if ((tid & 63) == 0)
      __hip_atomic_store(flags + (size_t)t * 256 + w * 4 + wid, 1u,
                         __ATOMIC_RELAXED, __HIP_MEMORY_SCOPE_AGENT);
  }
}

// ---------------- VAE head ----------------

__global__ void k_final(const float* __restrict__ hfin, const float* __restrict__ Wm,
                        const float* __restrict__ bm, const float* __restrict__ Wv,
                        const float* __restrict__ bv, const float* __restrict__ eps,
                        float* __restrict__ out) {
  int jb = blockIdx.x;
  int b = threadIdx.x & 63, u = threadIdx.x >> 6;
  int c0 = jb * 16 + u * 4;
  float am[4] = {0.f, 0.f, 0.f, 0.f};
  float av[4] = {0.f, 0.f, 0.f, 0.f};
  const float* hb = hfin + b * 1024;
  #pragma unroll 2
  for (int k = 0; k < 1024; ++k) {
    float hv = hb[k];
    float4 wm = *(const float4*)(Wm + (size_t)k * 1024 + c0);
    float4 wv = *(const float4*)(Wv + (size_t)k * 1024 + c0);
    am[0] += hv * wm.x; am[1] += hv * wm.y; am[2] += hv * wm.z; am[3] += hv * wm.w;
    av[0] += hv * wv.x; av[1] += hv * wv.y; av[2] += hv * wv.z; av[3] += hv * wv.w;
  }
  #pragma unroll
  for (int i = 0; i < 4; ++i) {
    int c = c0 + i;
    float mean = am[i] + bm[c];
    float lv = av[i] + bv[c];
    out[b * 1024 + c] = eps[b * 1024 + c] * __expf(0.5f * lv) + mean;
  }
}

// ---------------- launch ----------------

extern "C" void kernel_launch(void* const* d_in, const int* in_sizes, int n_in,
                              void* d_out, int out_size, void* d_ws, size_t ws_size,
                              hipStream_t stream) {
  const int*   tok = (const int*)d_in[0];
  const float* emb = (const float*)d_in[1];
  const float* W   = (const float*)d_in[2];
  const float* U   = (const float*)d_in[3];
  const float* bia = (const float*)d_in[4];
  const float* Wm  = (const float*)d_in[5];
  const float* bm  = (const float*)d_in[6];
  const float* Wv  = (const float*)d_in[7];
  const float* bv  = (const float*)d_in[8];
  const float* eps = (const float*)d_in[9];
  float* out = (float*)d_out;

  char* ws = (char*)d_ws;
  size_t off = 0;
  auto alloc = [&](size_t sz) { char* p = ws + off; off += (sz + 255) & ~(size_t)255; return p; };
  unsigned short* embb = (unsigned short*)alloc((size_t)VV * DD * 2);
  unsigned short* Wt   = (unsigned short*)alloc((size_t)FH * DD * 2);
  float*  bperm        = (float*)alloc((size_t)FH * 4);
  unsigned short* Uprep= (unsigned short*)alloc((size_t)64 * UBLK);
  unsigned short* xw   = (unsigned short*)alloc((size_t)BB * TT * FH * 2);
  unsigned short* hseq = (unsigned short*)alloc((size_t)TT * 131072);
  unsigned* flags      = (unsigned*)alloc((size_t)TT * 256 * 4);
  unsigned long long* mask64 = (unsigned long long*)alloc((size_t)TT * 8);
  float* hfin          = (float*)alloc((size_t)BB * HH * 4);
  (void)in_sizes; (void)n_in; (void)out_size; (void)ws_size;

  (void)hipMemsetAsync(flags, 0, (size_t)TT * 256 * 4, stream);
  k_cast_emb<<<8000, 256, 0, stream>>>(emb, embb);
  k_prep_w<<<4096, 128, 0, stream>>>(W, bia, Wt, bperm);
  k_prep_u<<<4096, 128, 0, stream>>>(U, Uprep);
  k_mask<<<1, 256, 0, stream>>>(tok, mask64);
  k_gemm_xw<<<4096, 256, 0, stream>>>(tok, embb, Wt, bperm, xw);
  (void)hipFuncSetAttribute((const void*)k_lstm, hipFuncAttributeMaxDynamicSharedMemorySize, LSTM_LDS);
  k_lstm<<<64, 256, LSTM_LDS, stream>>>(Uprep, xw, mask64, hseq, flags, hfin);
  k_final<<<64, 256, 0, stream>>>(hfin, Wm, bm, Wv, bv, eps, out);
}

// Round 8
// 3102.967 us; speedup vs baseline: 1.7469x; 1.1362x over previous
//
#include <hip/hip_runtime.h>
#include <stdint.h>

#define BB 64
#define TT 256
#define VV 32000
#define DD 512
#define HH 1024
#define FH 4096

// Padded U row stride: 2048 data bytes + 16 pad = 2064 (4-bank shift per row)
#define UROW 2064
#define UBLK (64 * UROW)   // 132096 bytes per WG

#define FLAG_PAIR 0x0000000100000001ULL

typedef float f32x4 __attribute__((ext_vector_type(4)));
typedef __bf16 bf16x8 __attribute__((ext_vector_type(8)));

typedef __attribute__((address_space(1))) void void_g;
typedef __attribute__((address_space(3))) void void_l;

static __device__ __forceinline__ void gload_lds16(const void* g, void* l) {
  __builtin_amdgcn_global_load_lds((const void_g*)g, (void_l*)l, 16, 0, 0);
}

static __device__ __forceinline__ unsigned short f2bf(float f) {
  union { float f; unsigned u; } x; x.f = f;
  unsigned r = x.u + 0x7FFFu + ((x.u >> 16) & 1u);
  return (unsigned short)(r >> 16);
}
static __device__ __forceinline__ float bf2f(unsigned short s) {
  union { unsigned u; float f; } x; x.u = ((unsigned)s) << 16;
  return x.f;
}
static __device__ __forceinline__ bf16x8 as_bf16x8(uint4 v) {
  union { uint4 u; bf16x8 b; } x; x.u = v; return x.b;
}
static __device__ __forceinline__ float sigm(float x) {
  return 1.f / (1.f + __expf(-x));
}
static __device__ __forceinline__ float tanh_f(float x) {
  x = fminf(15.f, fmaxf(-15.f, x));
  float e = __expf(2.f * x);
  return (e - 1.f) / (e + 1.f);
}
static __device__ __forceinline__ float get_bf_u2(uint2 v, int u) {
  unsigned r = (u < 2) ? v.x : v.y;
  return bf2f((unsigned short)((u & 1) ? (r >> 16) : (r & 0xFFFFu)));
}

// ---------------- prep kernels ----------------

__global__ void k_cast_emb(const float* __restrict__ src, unsigned short* __restrict__ dst) {
  size_t i = ((size_t)blockIdx.x * 256 + threadIdx.x) * 8;
  float4 a = *(const float4*)(src + i);
  float4 b = *(const float4*)(src + i + 4);
  uint4 o;
  o.x = (unsigned)f2bf(a.x) | ((unsigned)f2bf(a.y) << 16);
  o.y = (unsigned)f2bf(a.z) | ((unsigned)f2bf(a.w) << 16);
  o.z = (unsigned)f2bf(b.x) | ((unsigned)f2bf(b.y) << 16);
  o.w = (unsigned)f2bf(b.z) | ((unsigned)f2bf(b.w) << 16);
  *(uint4*)(dst + i) = o;
}

// W_t[n'][k] bf16 (transposed, column-permuted), b_perm[n'] f32.
// n' = w*64 + g*16 + jj  <->  n = g*1024 + w*16 + jj
__global__ void k_prep_w(const float* __restrict__ Wsrc, const float* __restrict__ bsrc,
                         unsigned short* __restrict__ Wt, float* __restrict__ bperm) {
  int np = blockIdx.x;
  int w = np >> 6, r = np & 63, g = r >> 4, jj = r & 15;
  int n = g * 1024 + w * 16 + jj;
  int k0 = threadIdx.x * 4;
  unsigned short q0 = f2bf(Wsrc[(size_t)(k0 + 0) * FH + n]);
  unsigned short q1 = f2bf(Wsrc[(size_t)(k0 + 1) * FH + n]);
  unsigned short q2 = f2bf(Wsrc[(size_t)(k0 + 2) * FH + n]);
  unsigned short q3 = f2bf(Wsrc[(size_t)(k0 + 3) * FH + n]);
  uint2 o;
  o.x = (unsigned)q0 | ((unsigned)q1 << 16);
  o.y = (unsigned)q2 | ((unsigned)q3 << 16);
  *(uint2*)((char*)Wt + (size_t)np * 1024 + (size_t)k0 * 2) = o;
  if (threadIdx.x == 0) bperm[np] = bsrc[n];
}

// U_prep: per WG w, padded-linear LDS image: row j (64 rows) at j*UROW,
// 2048 bytes of bf16 U[n(j,w)][k] + 16 pad bytes (zeroed).
__global__ void k_prep_u(const float* __restrict__ Usrc, unsigned short* __restrict__ Uprep) {
  int bid = blockIdx.x;            // 0..4095 = w*64 + j
  int j = bid & 63;
  int w = bid >> 6;
  int g = j >> 4, jj = j & 15;
  int n = g * 1024 + w * 16 + jj;
  int k0 = threadIdx.x * 8;
  unsigned p[4];
  #pragma unroll
  for (int h = 0; h < 4; ++h) {
    unsigned short e0 = f2bf(Usrc[(size_t)(k0 + 2 * h) * FH + n]);
    unsigned short e1 = f2bf(Usrc[(size_t)(k0 + 2 * h + 1) * FH + n]);
    p[h] = (unsigned)e0 | ((unsigned)e1 << 16);
  }
  uint4 o; o.x = p[0]; o.y = p[1]; o.z = p[2]; o.w = p[3];
  char* dst = (char*)Uprep + (size_t)w * UBLK + (size_t)j * UROW;
  *(uint4*)(dst + threadIdx.x * 16) = o;
  if (threadIdx.x == 0) { uint4 z = {0, 0, 0, 0}; *(uint4*)(dst + 2048) = z; }
}

__global__ void k_mask(const int* __restrict__ tok, unsigned long long* __restrict__ mask64) {
  int t = threadIdx.x;
  unsigned long long m = 0;
  for (int b = 0; b < BB; ++b)
    m |= (unsigned long long)(tok[b * TT + t] != 0) << b;
  mask64[t] = m;
}

// ---------------- xW GEMM (gather fused) ----------------

__launch_bounds__(256)
__global__ void k_gemm_xw(const int* __restrict__ tok, const unsigned short* __restrict__ embb,
                          const unsigned short* __restrict__ Wt, const float* __restrict__ bperm,
                          unsigned short* __restrict__ xw) {
  __shared__ char As[16384];
  __shared__ char Bs[16384];
  __shared__ int toks[128];
  int tid = threadIdx.x, lane = tid & 63, wid = tid >> 6;
  int bm = blockIdx.x >> 5, bn = blockIdx.x & 31;
  if (tid < 128) toks[tid] = tok[bm * 128 + tid];
  int wm = wid >> 1, wn = wid & 1;
  f32x4 vz = {0.f, 0.f, 0.f, 0.f};
  f32x4 acc[4][4];
  #pragma unroll
  for (int i = 0; i < 4; ++i)
    #pragma unroll
    for (int j = 0; j < 4; ++j) acc[i][j] = vz;

  int kls = (lane >> 4) * 16;
  for (int ks = 0; ks < 8; ++ks) {
    __syncthreads();
    #pragma unroll
    for (int c = 0; c < 4; ++c) {
      int o = wid * 4096 + c * 1024 + lane * 16;
      int m = o >> 7, kl = o & 127;
      const char* ga = (const char*)embb + (size_t)toks[m] * 1024 + ks * 128 + (kl ^ ((m & 7) << 4));
      gload_lds16(ga, As + o);
      const char* gb = (const char*)Wt + (size_t)(bn * 128 + m) * 1024 + ks * 128 + (kl ^ ((m & 7) << 4));
      gload_lds16(gb, Bs + o);
    }
    asm volatile("s_waitcnt vmcnt(0)" ::: "memory");
    __syncthreads();
    #pragma unroll
    for (int tk = 0; tk < 2; ++tk) {
      bf16x8 af[4], bf[4];
      int kb = tk * 64 + kls;
      #pragma unroll
      for (int mt = 0; mt < 4; ++mt) {
        int m = wm * 64 + mt * 16 + (lane & 15);
        af[mt] = *(const bf16x8*)(As + m * 128 + (kb ^ ((m & 7) << 4)));
      }
      #pragma unroll
      for (int nt = 0; nt < 4; ++nt) {
        int n = wn * 64 + nt * 16 + (lane & 15);
        bf[nt] = *(const bf16x8*)(Bs + n * 128 + (kb ^ ((n & 7) << 4)));
      }
      #pragma unroll
      for (int mt = 0; mt < 4; ++mt)
        #pragma unroll
        for (int nt = 0; nt < 4; ++nt)
          acc[mt][nt] = __builtin_amdgcn_mfma_f32_16x16x32_bf16(af[mt], bf[nt], acc[mt][nt], 0, 0, 0);
    }
  }
  #pragma unroll
  for (int nt = 0; nt < 4; ++nt) {
    int col = bn * 128 + wn * 64 + nt * 16 + (lane & 15);
    float bias = bperm[col];
    #pragma unroll
    for (int mt = 0; mt < 4; ++mt) {
      #pragma unroll
      for (int r = 0; r < 4; ++r) {
        int row = bm * 128 + wm * 64 + mt * 16 + (lane >> 4) * 4 + r;
        xw[(size_t)row * FH + col] = f2bf(acc[mt][nt][r] + bias);
      }
    }
  }
}

// ---------------- persistent LSTM scan ----------------
// 64 WGs, WG w owns h cols [16w,16w+16). U resident in LDS (padded rows).
// h broadcast via per-step monotonic global buffers. NEW: K dimension split
// into 8 pieces (128 k = 8 producer WGs each); consumers poll per-piece flags
// and MFMA each piece as it arrives (2-deep software pipeline, mod-3 bufs),
// with per-WG rotation of consumption order (p0 = w>>3) so the grid can run
// phase-staggered instead of as a monolithic per-step rendezvous.

#define LSTM_LDS (UBLK + 16640 + 4096 + 4096)

// Poll the 32 flags (16 u64) of piece P of step t-1
#define POLL16(P) do { \
  for (;;) { \
    unsigned long long v_ = __hip_atomic_load(fl64 + (P) * 16 + (lane & 15), \
                                              __ATOMIC_RELAXED, __HIP_MEMORY_SCOPE_AGENT); \
    if (__all(v_ == FLAG_PAIR)) break; \
    __builtin_amdgcn_s_sleep(1); \
  } \
  asm volatile("" ::: "memory"); \
} while (0)

// Issue the 8 A-fragment loads of piece P into buffer BUF (4 tk x 2 row-blocks)
#define ISSUE(BUF, P) do { \
  BUF[0] = *(const uint4*)(hp + b0B + (P) * 256);       \
  BUF[1] = *(const uint4*)(hp + b0B + (P) * 256 + 64);  \
  BUF[2] = *(const uint4*)(hp + b0B + (P) * 256 + 128); \
  BUF[3] = *(const uint4*)(hp + b0B + (P) * 256 + 192); \
  BUF[4] = *(const uint4*)(hp + b1B + (P) * 256);       \
  BUF[5] = *(const uint4*)(hp + b1B + (P) * 256 + 64);  \
  BUF[6] = *(const uint4*)(hp + b1B + (P) * 256 + 128); \
  BUF[7] = *(const uint4*)(hp + b1B + (P) * 256 + 192); \
} while (0)

// Consume piece P from BUF: 4 tk x 4 MFMAs
#define MFMA4(BUF, P) do { \
  _Pragma("unroll") \
  for (int q_ = 0; q_ < 4; ++q_) { \
    int tk_ = (P) * 4 + q_; \
    bf16x8 b0_ = *(const bf16x8*)(Us + bo0 + tk_ * 64); \
    bf16x8 b1_ = *(const bf16x8*)(Us + bo1 + tk_ * 64); \
    bf16x8 a0_ = as_bf16x8(BUF[q_]); \
    bf16x8 a1_ = as_bf16x8(BUF[4 + q_]); \
    a00 = __builtin_amdgcn_mfma_f32_16x16x32_bf16(a0_, b0_, a00, 0, 0, 0); \
    a01 = __builtin_amdgcn_mfma_f32_16x16x32_bf16(a0_, b1_, a01, 0, 0, 0); \
    a10 = __builtin_amdgcn_mfma_f32_16x16x32_bf16(a1_, b0_, a10, 0, 0, 0); \
    a11 = __builtin_amdgcn_mfma_f32_16x16x32_bf16(a1_, b1_, a11, 0, 0, 0); \
  } \
} while (0)

__launch_bounds__(256, 1)
__global__ void k_lstm(const unsigned short* __restrict__ Uprep, const unsigned short* __restrict__ xw,
                       const unsigned long long* __restrict__ mask64,
                       unsigned short* __restrict__ hseq, unsigned* __restrict__ flags,
                       float* __restrict__ hfin) {
  extern __shared__ char smem[];
  char* Us = smem;
  float* zl = (float*)(smem + UBLK);                 // [64][65] f32
  float* cb = (float*)(smem + UBLK + 16640);         // [64][16] f32
  float* ho = (float*)(smem + UBLK + 16640 + 4096);  // [64][16] f32
  int tid = threadIdx.x, lane = tid & 63, wid = tid >> 6;
  int w = blockIdx.x;

  {
    const char* src = (const char*)Uprep + (size_t)w * UBLK;
    #pragma unroll
    for (int c = 0; c < 32; ++c) {
      int o = c * 4096 + tid * 16;
      gload_lds16(src + o, Us + o);
    }
    if (wid == 0) {  // tail: 1024 bytes
      int o = 131072 + lane * 16;
      gload_lds16(src + o, Us + o);
    }
  }
  for (int i = tid; i < 1024; i += 256) { cb[i] = 0.f; ho[i] = 0.f; }
  asm volatile("s_waitcnt vmcnt(0)" ::: "memory");
  __syncthreads();

  int m2 = wid >> 1, n2 = wid & 1;
  int kls = (lane >> 4) * 16;
  int j0 = n2 * 32 + (lane & 15);
  int bo0 = j0 * UROW + kls;
  int bo1 = bo0 + 16 * UROW;
  int b0B = (m2 * 32 + (lane & 15)) * 2048 + kls;  // byte offset, row = 2048 B
  int b1B = b0B + 16 * 2048;
  int ub = tid >> 2, uq = tid & 3;
  int p0 = w >> 3;  // rotation: start with own region's piece

  for (int t = 0; t < TT; ++t) {
    uint2 xg[4];
    {
      const char* xp = (const char*)xw + (((size_t)ub * TT + t) * FH + w * 64) * 2;
      #pragma unroll
      for (int g = 0; g < 4; ++g) xg[g] = *(const uint2*)(xp + (g * 16 + uq * 4) * 2);
    }
    unsigned long long mb = mask64[t];
    f32x4 a00 = {0.f,0.f,0.f,0.f}, a01 = {0.f,0.f,0.f,0.f};
    f32x4 a10 = {0.f,0.f,0.f,0.f}, a11 = {0.f,0.f,0.f,0.f};

    if (t > 0) {
      const unsigned long long* fl64 =
          (const unsigned long long*)flags + (size_t)(t - 1) * 128;
      const char* hp = (const char*)hseq + (size_t)(t - 1) * 131072;
      uint4 A0[8], A1[8], A2[8];
      int P0 = p0 & 7,      P1 = (p0+1) & 7, P2 = (p0+2) & 7, P3 = (p0+3) & 7;
      int P4 = (p0+4) & 7,  P5 = (p0+5) & 7, P6 = (p0+6) & 7, P7 = (p0+7) & 7;
      POLL16(P0); ISSUE(A0, P0);
      POLL16(P1); ISSUE(A1, P1);
      POLL16(P2); ISSUE(A2, P2); MFMA4(A0, P0);
      POLL16(P3); ISSUE(A0, P3); MFMA4(A1, P1);
      POLL16(P4); ISSUE(A1, P4); MFMA4(A2, P2);
      POLL16(P5); ISSUE(A2, P5); MFMA4(A0, P3);
      POLL16(P6); ISSUE(A0, P6); MFMA4(A1, P4);
      POLL16(P7); ISSUE(A1, P7); MFMA4(A2, P5);
      MFMA4(A0, P6);
      MFMA4(A1, P7);
    }

    {
      int jb = n2 * 32 + (lane & 15);
      int rb = m2 * 32 + (lane >> 4) * 4;
      #pragma unroll
      for (int r = 0; r < 4; ++r) {
        zl[(rb + r) * 65 + jb]           = a00[r];
        zl[(rb + r) * 65 + jb + 16]      = a01[r];
        zl[(rb + 16 + r) * 65 + jb]      = a10[r];
        zl[(rb + 16 + r) * 65 + jb + 16] = a11[r];
      }
    }
    __syncthreads();

    {
      int jj0 = uq * 4;
      bool mk = (mb >> ub) & 1ull;
      unsigned long long pack = 0;
      float hv4[4];
      #pragma unroll
      for (int u = 0; u < 4; ++u) {
        int jj = jj0 + u;
        float zi = zl[ub * 65 + jj]      + get_bf_u2(xg[0], u);
        float zf = zl[ub * 65 + 16 + jj] + get_bf_u2(xg[1], u);
        float zg = zl[ub * 65 + 32 + jj] + get_bf_u2(xg[2], u);
        float zo = zl[ub * 65 + 48 + jj] + get_bf_u2(xg[3], u);
        float I = sigm(zi), F = sigm(zf), G = tanh_f(zg), O = sigm(zo);
        float cold = cb[ub * 16 + jj];
        float cn = F * cold + I * G;
        float hn = O * tanh_f(cn);
        if (!mk) { cn = cold; hn = ho[ub * 16 + jj]; }
        cb[ub * 16 + jj] = cn;
        ho[ub * 16 + jj] = hn;
        pack |= (unsigned long long)f2bf(hn) << (16 * u);
        hv4[u] = hn;
      }
      __hip_atomic_store(
        (unsigned long long*)(hseq + (size_t)t * 65536 + ub * 1024 + w * 16 + jj0),
        pack, __ATOMIC_RELAXED, __HIP_MEMORY_SCOPE_AGENT);
      if (t == TT - 1) {
        #pragma unroll
        for (int u = 0; u < 4; ++u) hfin[ub * 1024 + w * 16 + jj0 + u] = hv4[u];
      }
    }
    // per-wave drain + per-wave relaxed flag
    asm volatile("s_waitcnt vmcnt(0)" ::: "memory");
    if ((tid & 63) == 0)
      __hip_atomic_store(flags + (size_t)t * 256 + w * 4 + wid, 1u,
                         __ATOMIC_RELAXED, __HIP_MEMORY_SCOPE_AGENT);
  }
}

// ---------------- VAE head ----------------

__global__ void k_final(const float* __restrict__ hfin, const float* __restrict__ Wm,
                        const float* __restrict__ bm, const float* __restrict__ Wv,
                        const float* __restrict__ bv, const float* __restrict__ eps,
                        float* __restrict__ out) {
  int jb = blockIdx.x;
  int b = threadIdx.x & 63, u = threadIdx.x >> 6;
  int c0 = jb * 16 + u * 4;
  float am[4] = {0.f, 0.f, 0.f, 0.f};
  float av[4] = {0.f, 0.f, 0.f, 0.f};
  const float* hb = hfin + b * 1024;
  #pragma unroll 2
  for (int k = 0; k < 1024; ++k) {
    float hv = hb[k];
    float4 wm = *(const float4*)(Wm + (size_t)k * 1024 + c0);
    float4 wv = *(const float4*)(Wv + (size_t)k * 1024 + c0);
    am[0] += hv * wm.x; am[1] += hv * wm.y; am[2] += hv * wm.z; am[3] += hv * wm.w;
    av[0] += hv * wv.x; av[1] += hv * wv.y; av[2] += hv * wv.z; av[3] += hv * wv.w;
  }
  #pragma unroll
  for (int i = 0; i < 4; ++i) {
    int c = c0 + i;
    float mean = am[i] + bm[c];
    float lv = av[i] + bv[c];
    out[b * 1024 + c] = eps[b * 1024 + c] * __expf(0.5f * lv) + mean;
  }
}

// ---------------- launch ----------------

extern "C" void kernel_launch(void* const* d_in, const int* in_sizes, int n_in,
                              void* d_out, int out_size, void* d_ws, size_t ws_size,
                              hipStream_t stream) {
  const int*   tok = (const int*)d_in[0];
  const float* emb = (const float*)d_in[1];
  const float* W   = (const float*)d_in[2];
  const float* U   = (const float*)d_in[3];
  const float* bia = (const float*)d_in[4];
  const float* Wm  = (const float*)d_in[5];
  const float* bm  = (const float*)d_in[6];
  const float* Wv  = (const float*)d_in[7];
  const float* bv  = (const float*)d_in[8];
  const float* eps = (const float*)d_in[9];
  float* out = (float*)d_out;

  char* ws = (char*)d_ws;
  size_t off = 0;
  auto alloc = [&](size_t sz) { char* p = ws + off; off += (sz + 255) & ~(size_t)255; return p; };
  unsigned short* embb = (unsigned short*)alloc((size_t)VV * DD * 2);
  unsigned short* Wt   = (unsigned short*)alloc((size_t)FH * DD * 2);
  float*  bperm        = (float*)alloc((size_t)FH * 4);
  unsigned short* Uprep= (unsigned short*)alloc((size_t)64 * UBLK);
  unsigned short* xw   = (unsigned short*)alloc((size_t)BB * TT * FH * 2);
  unsigned short* hseq = (unsigned short*)alloc((size_t)TT * 131072);
  unsigned* flags      = (unsigned*)alloc((size_t)TT * 256 * 4);
  unsigned long long* mask64 = (unsigned long long*)alloc((size_t)TT * 8);
  float* hfin          = (float*)alloc((size_t)BB * HH * 4);
  (void)in_sizes; (void)n_in; (void)out_size; (void)ws_size;

  (void)hipMemsetAsync(flags, 0, (size_t)TT * 256 * 4, stream);
  k_cast_emb<<<8000, 256, 0, stream>>>(emb, embb);
  k_prep_w<<<4096, 128, 0, stream>>>(W, bia, Wt, bperm);
  k_prep_u<<<4096, 128, 0, stream>>>(U, Uprep);
  k_mask<<<1, 256, 0, stream>>>(tok, mask64);
  k_gemm_xw<<<4096, 256, 0, stream>>>(tok, embb, Wt, bperm, xw);
  (void)hipFuncSetAttribute((const void*)k_lstm, hipFuncAttributeMaxDynamicSharedMemorySize, LSTM_LDS);
  k_lstm<<<64, 256, LSTM_LDS, stream>>>(Uprep, xw, mask64, hseq, flags, hfin);
  k_final<<<64, 256, 0, stream>>>(hfin, Wm, bm, Wv, bv, eps, out);
}

// Round 9
// 2590.019 us; speedup vs baseline: 2.0928x; 1.1980x over previous
//
#include <hip/hip_runtime.h>
#include <stdint.h>

#define BB 64
#define TT 256
#define VV 32000
#define DD 512
#define HH 1024
#define FH 4096

#define UROW 2064
#define UBLK (64 * UROW)   // 132096 bytes per WG
#define RSTRIDE (TT * FH * 2)  // xw row-block stride per batch

#define FLAG_PAIR 0x0000000100000001ULL

typedef float f32x4 __attribute__((ext_vector_type(4)));
typedef __bf16 bf16x8 __attribute__((ext_vector_type(8)));

typedef __attribute__((address_space(1))) void void_g;
typedef __attribute__((address_space(3))) void void_l;

static __device__ __forceinline__ void gload_lds16(const void* g, void* l) {
  __builtin_amdgcn_global_load_lds((const void_g*)g, (void_l*)l, 16, 0, 0);
}

static __device__ __forceinline__ unsigned short f2bf(float f) {
  union { float f; unsigned u; } x; x.f = f;
  unsigned r = x.u + 0x7FFFu + ((x.u >> 16) & 1u);
  return (unsigned short)(r >> 16);
}
static __device__ __forceinline__ float bf2f(unsigned short s) {
  union { unsigned u; float f; } x; x.u = ((unsigned)s) << 16;
  return x.f;
}
static __device__ __forceinline__ bf16x8 as_bf16x8(uint4 v) {
  union { uint4 u; bf16x8 b; } x; x.u = v; return x.b;
}
static __device__ __forceinline__ float sigm(float x) {
  return 1.f / (1.f + __expf(-x));
}
static __device__ __forceinline__ float tanh_f(float x) {
  x = fminf(15.f, fmaxf(-15.f, x));
  float e = __expf(2.f * x);
  return (e - 1.f) / (e + 1.f);
}

// ---------------- prep kernels ----------------

__global__ void k_cast_emb(const float* __restrict__ src, unsigned short* __restrict__ dst) {
  size_t i = ((size_t)blockIdx.x * 256 + threadIdx.x) * 8;
  float4 a = *(const float4*)(src + i);
  float4 b = *(const float4*)(src + i + 4);
  uint4 o;
  o.x = (unsigned)f2bf(a.x) | ((unsigned)f2bf(a.y) << 16);
  o.y = (unsigned)f2bf(a.z) | ((unsigned)f2bf(a.w) << 16);
  o.z = (unsigned)f2bf(b.x) | ((unsigned)f2bf(b.y) << 16);
  o.w = (unsigned)f2bf(b.z) | ((unsigned)f2bf(b.w) << 16);
  *(uint4*)(dst + i) = o;
}

// W_t[n'][k] bf16 (transposed, column-permuted), b_perm[n'] f32.
// n' = w*64 + g*16 + jj  <->  n = g*1024 + w*16 + jj
__global__ void k_prep_w(const float* __restrict__ Wsrc, const float* __restrict__ bsrc,
                         unsigned short* __restrict__ Wt, float* __restrict__ bperm) {
  int np = blockIdx.x;
  int w = np >> 6, r = np & 63, g = r >> 4, jj = r & 15;
  int n = g * 1024 + w * 16 + jj;
  int k0 = threadIdx.x * 4;
  unsigned short q0 = f2bf(Wsrc[(size_t)(k0 + 0) * FH + n]);
  unsigned short q1 = f2bf(Wsrc[(size_t)(k0 + 1) * FH + n]);
  unsigned short q2 = f2bf(Wsrc[(size_t)(k0 + 2) * FH + n]);
  unsigned short q3 = f2bf(Wsrc[(size_t)(k0 + 3) * FH + n]);
  uint2 o;
  o.x = (unsigned)q0 | ((unsigned)q1 << 16);
  o.y = (unsigned)q2 | ((unsigned)q3 << 16);
  *(uint2*)((char*)Wt + (size_t)np * 1024 + (size_t)k0 * 2) = o;
  if (threadIdx.x == 0) bperm[np] = bsrc[n];
}

// U_prep: per WG w, padded-linear LDS image: row j (64 rows) at j*UROW
__global__ void k_prep_u(const float* __restrict__ Usrc, unsigned short* __restrict__ Uprep) {
  int bid = blockIdx.x;            // 0..4095 = w*64 + j
  int j = bid & 63;
  int w = bid >> 6;
  int g = j >> 4, jj = j & 15;
  int n = g * 1024 + w * 16 + jj;
  int k0 = threadIdx.x * 8;
  unsigned p[4];
  #pragma unroll
  for (int h = 0; h < 4; ++h) {
    unsigned short e0 = f2bf(Usrc[(size_t)(k0 + 2 * h) * FH + n]);
    unsigned short e1 = f2bf(Usrc[(size_t)(k0 + 2 * h + 1) * FH + n]);
    p[h] = (unsigned)e0 | ((unsigned)e1 << 16);
  }
  uint4 o; o.x = p[0]; o.y = p[1]; o.z = p[2]; o.w = p[3];
  char* dst = (char*)Uprep + (size_t)w * UBLK + (size_t)j * UROW;
  *(uint4*)(dst + threadIdx.x * 16) = o;
  if (threadIdx.x == 0) { uint4 z = {0, 0, 0, 0}; *(uint4*)(dst + 2048) = z; }
}

__global__ void k_mask(const int* __restrict__ tok, unsigned long long* __restrict__ mask64) {
  int t = threadIdx.x;
  unsigned long long m = 0;
  for (int b = 0; b < BB; ++b)
    m |= (unsigned long long)(tok[b * TT + t] != 0) << b;
  mask64[t] = m;
}

// ---------------- xW GEMM (gather fused) ----------------
// Output layout permuted within each 64-col block: offset = jj*4 + g
// (4 gates adjacent per jj) so k_lstm lane (jj) reads one uint2.

__launch_bounds__(256)
__global__ void k_gemm_xw(const int* __restrict__ tok, const unsigned short* __restrict__ embb,
                          const unsigned short* __restrict__ Wt, const float* __restrict__ bperm,
                          unsigned short* __restrict__ xw) {
  __shared__ char As[16384];
  __shared__ char Bs[16384];
  __shared__ int toks[128];
  int tid = threadIdx.x, lane = tid & 63, wid = tid >> 6;
  int bm = blockIdx.x >> 5, bn = blockIdx.x & 31;
  if (tid < 128) toks[tid] = tok[bm * 128 + tid];
  int wm = wid >> 1, wn = wid & 1;
  f32x4 vz = {0.f, 0.f, 0.f, 0.f};
  f32x4 acc[4][4];
  #pragma unroll
  for (int i = 0; i < 4; ++i)
    #pragma unroll
    for (int j = 0; j < 4; ++j) acc[i][j] = vz;

  int kls = (lane >> 4) * 16;
  for (int ks = 0; ks < 8; ++ks) {
    __syncthreads();
    #pragma unroll
    for (int c = 0; c < 4; ++c) {
      int o = wid * 4096 + c * 1024 + lane * 16;
      int m = o >> 7, kl = o & 127;
      const char* ga = (const char*)embb + (size_t)toks[m] * 1024 + ks * 128 + (kl ^ ((m & 7) << 4));
      gload_lds16(ga, As + o);
      const char* gb = (const char*)Wt + (size_t)(bn * 128 + m) * 1024 + ks * 128 + (kl ^ ((m & 7) << 4));
      gload_lds16(gb, Bs + o);
    }
    asm volatile("s_waitcnt vmcnt(0)" ::: "memory");
    __syncthreads();
    #pragma unroll
    for (int tk = 0; tk < 2; ++tk) {
      bf16x8 af[4], bf[4];
      int kb = tk * 64 + kls;
      #pragma unroll
      for (int mt = 0; mt < 4; ++mt) {
        int m = wm * 64 + mt * 16 + (lane & 15);
        af[mt] = *(const bf16x8*)(As + m * 128 + (kb ^ ((m & 7) << 4)));
      }
      #pragma unroll
      for (int nt = 0; nt < 4; ++nt) {
        int n = wn * 64 + nt * 16 + (lane & 15);
        bf[nt] = *(const bf16x8*)(Bs + n * 128 + (kb ^ ((n & 7) << 4)));
      }
      #pragma unroll
      for (int mt = 0; mt < 4; ++mt)
        #pragma unroll
        for (int nt = 0; nt < 4; ++nt)
          acc[mt][nt] = __builtin_amdgcn_mfma_f32_16x16x32_bf16(af[mt], bf[nt], acc[mt][nt], 0, 0, 0);
    }
  }
  #pragma unroll
  for (int nt = 0; nt < 4; ++nt) {
    int col = bn * 128 + wn * 64 + nt * 16 + (lane & 15);
    float bias = bperm[col];
    int pcol = (col & ~63) | ((lane & 15) * 4 + nt);  // gate-interleaved layout
    #pragma unroll
    for (int mt = 0; mt < 4; ++mt) {
      #pragma unroll
      for (int r = 0; r < 4; ++r) {
        int row = bm * 128 + wm * 64 + mt * 16 + (lane >> 4) * 4 + r;
        xw[(size_t)row * FH + pcol] = f2bf(acc[mt][nt][r] + bias);
      }
    }
  }
}

// ---------------- persistent LSTM scan (ROWWAVE) ----------------
// 64 WGs x 4 independent waves. Wave wid owns batch rows [16wid,16wid+16):
// A = those rows' h (global), B = all 64 z-cols of U (LDS). MFMA output
// holds all 4 gates per (b,jj) in one lane -> gates in-register, NO
// __syncthreads in the loop. h packed via wave-local LDS shuffle, stored
// with agent atomics; per-wave flags; per-piece polls with wave rotation.

#define LSTM_LDS (UBLK + 4352 + 4352 + 2560)

#define POLL16(P) do { \
  for (;;) { \
    unsigned long long v_ = __hip_atomic_load(fl64 + (P) * 16 + (lane & 15), \
                                              __ATOMIC_RELAXED, __HIP_MEMORY_SCOPE_AGENT); \
    if (__all(v_ == FLAG_PAIR)) break; \
    __builtin_amdgcn_s_sleep(1); \
  } \
  asm volatile("" ::: "memory"); \
} while (0)

#define ISSUE(BUF, P) do { \
  BUF[0] = *(const uint4*)(hp + aB + (P) * 256);       \
  BUF[1] = *(const uint4*)(hp + aB + (P) * 256 + 64);  \
  BUF[2] = *(const uint4*)(hp + aB + (P) * 256 + 128); \
  BUF[3] = *(const uint4*)(hp + aB + (P) * 256 + 192); \
} while (0)

#define MFMA4(BUF, P) do { \
  _Pragma("unroll") \
  for (int q_ = 0; q_ < 4; ++q_) { \
    int tk_ = (P) * 4 + q_; \
    bf16x8 a_  = as_bf16x8(BUF[q_]); \
    bf16x8 b0_ = *(const bf16x8*)(Us + boi + tk_ * 64); \
    bf16x8 b1_ = *(const bf16x8*)(Us + bof + tk_ * 64); \
    bf16x8 b2_ = *(const bf16x8*)(Us + bog + tk_ * 64); \
    bf16x8 b3_ = *(const bf16x8*)(Us + boo + tk_ * 64); \
    acc0 = __builtin_amdgcn_mfma_f32_16x16x32_bf16(a_, b0_, acc0, 0, 0, 0); \
    acc1 = __builtin_amdgcn_mfma_f32_16x16x32_bf16(a_, b1_, acc1, 0, 0, 0); \
    acc2 = __builtin_amdgcn_mfma_f32_16x16x32_bf16(a_, b2_, acc2, 0, 0, 0); \
    acc3 = __builtin_amdgcn_mfma_f32_16x16x32_bf16(a_, b3_, acc3, 0, 0, 0); \
  } \
} while (0)

#define GATE(R, XG) do { \
  int br_ = wid * 16 + hi * 4 + (R); \
  float zi_ = acc0[R] + bf2f((unsigned short)((XG).x & 0xFFFFu)); \
  float zf_ = acc1[R] + bf2f((unsigned short)((XG).x >> 16)); \
  float zg_ = acc2[R] + bf2f((unsigned short)((XG).y & 0xFFFFu)); \
  float zo_ = acc3[R] + bf2f((unsigned short)((XG).y >> 16)); \
  float I_ = sigm(zi_), F_ = sigm(zf_), G_ = tanh_f(zg_), O_ = sigm(zo_); \
  float co_ = cb[cbb + (R) * 17]; \
  float cn_ = F_ * co_ + I_ * G_; \
  float hn_ = O_ * tanh_f(cn_); \
  if (!((mb >> br_) & 1ull)) { cn_ = co_; hn_ = ho[cbb + (R) * 17]; } \
  cb[cbb + (R) * 17] = cn_; ho[cbb + (R) * 17] = hn_; \
  hs[hw + (R) * 20] = f2bf(hn_); \
  if (t == TT - 1) hfin[(size_t)br_ * 1024 + w * 16 + jj] = hn_; \
} while (0)

__launch_bounds__(256, 1)
__global__ void k_lstm(const unsigned short* __restrict__ Uprep, const unsigned short* __restrict__ xw,
                       const unsigned long long* __restrict__ mask64,
                       unsigned short* __restrict__ hseq, unsigned* __restrict__ flags,
                       float* __restrict__ hfin) {
  extern __shared__ char smem[];
  char* Us = smem;
  float* cb = (float*)(smem + UBLK);                   // [64][17] f32
  float* ho = (float*)(smem + UBLK + 4352);            // [64][17] f32
  unsigned short* hs = (unsigned short*)(smem + UBLK + 8704);  // [64][20] bf16
  int tid = threadIdx.x, lane = tid & 63, wid = tid >> 6;
  int w = blockIdx.x;

  {
    const char* src = (const char*)Uprep + (size_t)w * UBLK;
    #pragma unroll
    for (int c = 0; c < 32; ++c) {
      int o = c * 4096 + tid * 16;
      gload_lds16(src + o, Us + o);
    }
    if (wid == 0) {  // tail: 1024 bytes
      int o = 131072 + lane * 16;
      gload_lds16(src + o, Us + o);
    }
  }
  for (int i = tid; i < 1088; i += 256) { cb[i] = 0.f; ho[i] = 0.f; }
  asm volatile("s_waitcnt vmcnt(0)" ::: "memory");
  __syncthreads();

  int jj = lane & 15, hi = lane >> 4;
  int kls = hi * 16;
  int aB  = (wid * 16 + jj) * 2048 + kls;      // A-row byte offset in hseq step buf
  int boi = (jj)      * UROW + kls;            // B bases: gates i,f,g,o
  int bof = (16 + jj) * UROW + kls;
  int bog = (32 + jj) * UROW + kls;
  int boo = (48 + jj) * UROW + kls;
  int cbb = (wid * 16 + hi * 4) * 17 + jj;
  int hw  = (wid * 16 + hi * 4) * 20 + jj;
  int hr  = (wid * 16 + (lane >> 2)) * 20 + (lane & 3) * 4;
  int pb  = (wid * 16 + (lane >> 2)) * 1024 + w * 16 + (lane & 3) * 4;
  const char* xb = (const char*)xw + ((size_t)(wid * 16 + hi * 4) * TT * FH + w * 64 + jj * 4) * 2;
  int p0v = ((w >> 3) + wid * 2) & 7;

  uint2 xg0 = *(const uint2*)(xb + 0 * RSTRIDE);
  uint2 xg1 = *(const uint2*)(xb + 1 * RSTRIDE);
  uint2 xg2 = *(const uint2*)(xb + 2 * RSTRIDE);
  uint2 xg3 = *(const uint2*)(xb + 3 * RSTRIDE);

  for (int t = 0; t < TT; ++t) {
    unsigned long long mb = mask64[t];
    f32x4 acc0 = {0.f,0.f,0.f,0.f}, acc1 = {0.f,0.f,0.f,0.f};
    f32x4 acc2 = {0.f,0.f,0.f,0.f}, acc3 = {0.f,0.f,0.f,0.f};
    uint2 xn0, xn1, xn2, xn3;
    int tn = (t + 1) & 255;

    if (t > 0) {
      const unsigned long long* fl64 =
          (const unsigned long long*)flags + (size_t)(t - 1) * 128;
      const char* hp = (const char*)hseq + (size_t)(t - 1) * 131072;
      uint4 A0[4], A1[4], A2[4];
      int P0 = p0v, P1 = (p0v+1)&7, P2 = (p0v+2)&7, P3 = (p0v+3)&7;
      int P4 = (p0v+4)&7, P5 = (p0v+5)&7, P6 = (p0v+6)&7, P7 = (p0v+7)&7;
      POLL16(P0); ISSUE(A0, P0);
      POLL16(P1); ISSUE(A1, P1);
      POLL16(P2); ISSUE(A2, P2); MFMA4(A0, P0);
      POLL16(P3); ISSUE(A0, P3); MFMA4(A1, P1);
      POLL16(P4); ISSUE(A1, P4); MFMA4(A2, P2);
      POLL16(P5); ISSUE(A2, P5); MFMA4(A0, P3);
      POLL16(P6); ISSUE(A0, P6); MFMA4(A1, P4);
      POLL16(P7); ISSUE(A1, P7); MFMA4(A2, P5);
      xn0 = *(const uint2*)(xb + 0 * RSTRIDE + (size_t)tn * (FH * 2));
      xn1 = *(const uint2*)(xb + 1 * RSTRIDE + (size_t)tn * (FH * 2));
      xn2 = *(const uint2*)(xb + 2 * RSTRIDE + (size_t)tn * (FH * 2));
      xn3 = *(const uint2*)(xb + 3 * RSTRIDE + (size_t)tn * (FH * 2));
      MFMA4(A0, P6);
      MFMA4(A1, P7);
    } else {
      xn0 = *(const uint2*)(xb + 0 * RSTRIDE + (size_t)tn * (FH * 2));
      xn1 = *(const uint2*)(xb + 1 * RSTRIDE + (size_t)tn * (FH * 2));
      xn2 = *(const uint2*)(xb + 2 * RSTRIDE + (size_t)tn * (FH * 2));
      xn3 = *(const uint2*)(xb + 3 * RSTRIDE + (size_t)tn * (FH * 2));
    }

    GATE(0, xg0);
    GATE(1, xg1);
    GATE(2, xg2);
    GATE(3, xg3);

    {
      unsigned long long pv = *(const unsigned long long*)(hs + hr);
      __hip_atomic_store((unsigned long long*)(hseq + (size_t)t * 65536 + pb),
                         pv, __ATOMIC_RELAXED, __HIP_MEMORY_SCOPE_AGENT);
    }
    asm volatile("s_waitcnt vmcnt(0)" ::: "memory");
    if (lane == 0)
      __hip_atomic_store(flags + (size_t)t * 256 + w * 4 + wid, 1u,
                         __ATOMIC_RELAXED, __HIP_MEMORY_SCOPE_AGENT);
    xg0 = xn0; xg1 = xn1; xg2 = xn2; xg3 = xn3;
  }
}

// ---------------- VAE head ----------------

__global__ void k_final(const float* __restrict__ hfin, const float* __restrict__ Wm,
                        const float* __restrict__ bm, const float* __restrict__ Wv,
                        const float* __restrict__ bv, const float* __restrict__ eps,
                        float* __restrict__ out) {
  int jb = blockIdx.x;
  int b = threadIdx.x & 63, u = threadIdx.x >> 6;
  int c0 = jb * 16 + u * 4;
  float am[4] = {0.f, 0.f, 0.f, 0.f};
  float av[4] = {0.f, 0.f, 0.f, 0.f};
  const float* hb = hfin + b * 1024;
  #pragma unroll 2
  for (int k = 0; k < 1024; ++k) {
    float hv = hb[k];
    float4 wm = *(const float4*)(Wm + (size_t)k * 1024 + c0);
    float4 wv = *(const float4*)(Wv + (size_t)k * 1024 + c0);
    am[0] += hv * wm.x; am[1] += hv * wm.y; am[2] += hv * wm.z; am[3] += hv * wm.w;
    av[0] += hv * wv.x; av[1] += hv * wv.y; av[2] += hv * wv.z; av[3] += hv * wv.w;
  }
  #pragma unroll
  for (int i = 0; i < 4; ++i) {
    int c = c0 + i;
    float mean = am[i] + bm[c];
    float lv = av[i] + bv[c];
    out[b * 1024 + c] = eps[b * 1024 + c] * __expf(0.5f * lv) + mean;
  }
}

// ---------------- launch ----------------

extern "C" void kernel_launch(void* const* d_in, const int* in_sizes, int n_in,
                              void* d_out, int out_size, void* d_ws, size_t ws_size,
                              hipStream_t stream) {
  const int*   tok = (const int*)d_in[0];
  const float* emb = (const float*)d_in[1];
  const float* W   = (const float*)d_in[2];
  const float* U   = (const float*)d_in[3];
  const float* bia = (const float*)d_in[4];
  const float* Wm  = (const float*)d_in[5];
  const float* bm  = (const float*)d_in[6];
  const float* Wv  = (const float*)d_in[7];
  const float* bv  = (const float*)d_in[8];
  const float* eps = (const float*)d_in[9];
  float* out = (float*)d_out;

  char* ws = (char*)d_ws;
  size_t off = 0;
  auto alloc = [&](size_t sz) { char* p = ws + off; off += (sz + 255) & ~(size_t)255; return p; };
  unsigned short* embb = (unsigned short*)alloc((size_t)VV * DD * 2);
  unsigned short* Wt   = (unsigned short*)alloc((size_t)FH * DD * 2);
  float*  bperm        = (float*)alloc((size_t)FH * 4);
  unsigned short* Uprep= (unsigned short*)alloc((size_t)64 * UBLK);
  unsigned short* xw   = (unsigned short*)alloc((size_t)BB * TT * FH * 2);
  unsigned short* hseq = (unsigned short*)alloc((size_t)TT * 131072);
  unsigned* flags      = (unsigned*)alloc((size_t)TT * 256 * 4);
  unsigned long long* mask64 = (unsigned long long*)alloc((size_t)TT * 8);
  float* hfin          = (float*)alloc((size_t)BB * HH * 4);
  (void)in_sizes; (void)n_in; (void)out_size; (void)ws_size;

  (void)hipMemsetAsync(flags, 0, (size_t)TT * 256 * 4, stream);
  k_cast_emb<<<8000, 256, 0, stream>>>(emb, embb);
  k_prep_w<<<4096, 128, 0, stream>>>(W, bia, Wt, bperm);
  k_prep_u<<<4096, 128, 0, stream>>>(U, Uprep);
  k_mask<<<1, 256, 0, stream>>>(tok, mask64);
  k_gemm_xw<<<4096, 256, 0, stream>>>(tok, embb, Wt, bperm, xw);
  (void)hipFuncSetAttribute((const void*)k_lstm, hipFuncAttributeMaxDynamicSharedMemorySize, LSTM_LDS);
  k_lstm<<<64, 256, LSTM_LDS, stream>>>(Uprep, xw, mask64, hseq, flags, hfin);
  k_final<<<64, 256, 0, stream>>>(hfin, Wm, bm, Wv, bv, eps, out);
}